// Round 1
// baseline (1125.506 us; speedup 1.0000x reference)
//
#include <hip/hip_runtime.h>
#include <cstdint>

#define H_DIM 2048
#define B_ROWS 8192

static __device__ __forceinline__ float4 ld4(const float* p) {
  return *reinterpret_cast<const float4*>(p);
}

// ---------------- K1: normalize protos (64 rows of 2048) ----------------
__global__ __launch_bounds__(256) void proto_norm_kernel(const float* __restrict__ protos,
                                                         float* __restrict__ pn) {
  const int k = blockIdx.x;
  const int tid = threadIdx.x;
  const float* row = protos + (size_t)k * H_DIM;
  float4 v0 = ld4(row + tid * 8);
  float4 v1 = ld4(row + tid * 8 + 4);
  float ss = v0.x*v0.x + v0.y*v0.y + v0.z*v0.z + v0.w*v0.w
           + v1.x*v1.x + v1.y*v1.y + v1.z*v1.z + v1.w*v1.w;
  for (int o = 32; o > 0; o >>= 1) ss += __shfl_down(ss, o);
  __shared__ float red[4];
  const int lane = tid & 63, wv = tid >> 6;
  if (lane == 0) red[wv] = ss;
  __syncthreads();
  const float tot = red[0] + red[1] + red[2] + red[3];
  const float inv = 1.0f / fmaxf(sqrtf(tot), 1e-12f);
  float* orow = pn + (size_t)k * H_DIM;
  *reinterpret_cast<float4*>(orow + tid*8)     = make_float4(v0.x*inv, v0.y*inv, v0.z*inv, v0.w*inv);
  *reinterpret_cast<float4*>(orow + tid*8 + 4) = make_float4(v1.x*inv, v1.y*inv, v1.z*inv, v1.w*inv);
}

// ---------------- K2: fp32 SGEMM, 128x128x16 tile, 256 threads ----------------
// C[m][n] = sum_k Aval(m,k) * B[k*N+n] (* Msk if MASKB)
// AKMAJOR: Aval(m,k) = A[k*lda + m]  (TN form, no LDS transpose)
// else   : Aval(m,k) = A[m*lda + k]  (NN form, transpose on LDS store)
template<bool AKMAJOR, bool MASKB>
__global__ __launch_bounds__(256) void sgemm128(const float* __restrict__ A,
                                                const float* __restrict__ B,
                                                const float* __restrict__ Msk,
                                                float* __restrict__ C,
                                                int M, int N, int K, int lda) {
  __shared__ float As[16][132];
  __shared__ float Bs[16][132];
  const int tid = threadIdx.x;
  const int tx = tid & 15, ty = tid >> 4;
  const int m0 = blockIdx.y * 128, n0 = blockIdx.x * 128;
  float acc[8][8];
#pragma unroll
  for (int i = 0; i < 8; ++i)
#pragma unroll
    for (int j = 0; j < 8; ++j) acc[i][j] = 0.f;

  for (int k0 = 0; k0 < K; k0 += 16) {
    if constexpr (AKMAJOR) {
#pragma unroll
      for (int t = 0; t < 2; ++t) {
        const int f = tid + t * 256;
        const int kr = f >> 5, c4 = (f & 31) << 2;
        float4 v = ld4(&A[(size_t)(k0 + kr) * lda + m0 + c4]);
        *reinterpret_cast<float4*>(&As[kr][c4]) = v;
      }
    } else {
#pragma unroll
      for (int t = 0; t < 2; ++t) {
        const int f = tid + t * 256;
        const int r = f >> 2, c4 = (f & 3) << 2;
        float4 v = ld4(&A[(size_t)(m0 + r) * lda + k0 + c4]);
        As[c4 + 0][r] = v.x; As[c4 + 1][r] = v.y;
        As[c4 + 2][r] = v.z; As[c4 + 3][r] = v.w;
      }
    }
#pragma unroll
    for (int t = 0; t < 2; ++t) {
      const int f = tid + t * 256;
      const int kr = f >> 5, c4 = (f & 31) << 2;
      float4 v = ld4(&B[(size_t)(k0 + kr) * N + n0 + c4]);
      if constexpr (MASKB) {
        float4 mv = ld4(&Msk[(size_t)(k0 + kr) * N + n0 + c4]);
        v.x *= mv.x; v.y *= mv.y; v.z *= mv.z; v.w *= mv.w;
      }
      *reinterpret_cast<float4*>(&Bs[kr][c4]) = v;
    }
    __syncthreads();
#pragma unroll
    for (int k = 0; k < 16; ++k) {
      float a[8], b[8];
      *reinterpret_cast<float4*>(&a[0]) = *reinterpret_cast<float4*>(&As[k][ty * 8]);
      *reinterpret_cast<float4*>(&a[4]) = *reinterpret_cast<float4*>(&As[k][ty * 8 + 4]);
      *reinterpret_cast<float4*>(&b[0]) = *reinterpret_cast<float4*>(&Bs[k][tx * 4]);
      *reinterpret_cast<float4*>(&b[4]) = *reinterpret_cast<float4*>(&Bs[k][tx * 4 + 64]);
#pragma unroll
      for (int i = 0; i < 8; ++i)
#pragma unroll
        for (int j = 0; j < 8; ++j)
          acc[i][j] = fmaf(a[i], b[j], acc[i][j]);
    }
    __syncthreads();
  }
#pragma unroll
  for (int i = 0; i < 8; ++i) {
    const size_t row = (size_t)(m0 + ty * 8 + i) * N;
    *reinterpret_cast<float4*>(&C[row + n0 + tx * 4]) =
        make_float4(acc[i][0], acc[i][1], acc[i][2], acc[i][3]);
    *reinterpret_cast<float4*>(&C[row + n0 + 64 + tx * 4]) =
        make_float4(acc[i][4], acc[i][5], acc[i][6], acc[i][7]);
  }
}

// ---------------- K3: fused norm + sim + softmax + entropy + argmax + action ----------------
// 16 rows/block, 256 threads: thread (r=tid>>4, c=tid&15) owns row r, protos {c, c+16, c+32, c+48}
__global__ __launch_bounds__(256) void tail_kernel(const float* __restrict__ hsyn,
                                                   const float* __restrict__ pn,
                                                   const float* __restrict__ gates,
                                                   const float* __restrict__ actions,
                                                   float* __restrict__ outAct,
                                                   float* __restrict__ entSlot,
                                                   float* __restrict__ outPid) {
  __shared__ float pl[64][132];
  __shared__ float hl[16][132];
  __shared__ float al[64][68];
  __shared__ float wl[16][68];
  const int tid = threadIdx.x;
  const int c = tid & 15, r = tid >> 4;
  const int b0 = blockIdx.x * 16;

#pragma unroll
  for (int t = 0; t < 4; ++t) {
    const int f = tid + t * 256;
    const int k = f >> 4, c4 = (f & 15) << 2;
    *reinterpret_cast<float4*>(&al[k][c4]) = ld4(&actions[k * 64 + c4]);
  }

  float sim[4] = {0.f, 0.f, 0.f, 0.f};
  float ss = 0.f;

  for (int i0 = 0; i0 < H_DIM; i0 += 128) {
    __syncthreads();
#pragma unroll
    for (int t = 0; t < 8; ++t) {
      const int f = tid + t * 256;
      const int k = f >> 5, c4 = (f & 31) << 2;
      *reinterpret_cast<float4*>(&pl[k][c4]) = ld4(&pn[(size_t)k * H_DIM + i0 + c4]);
    }
#pragma unroll
    for (int t = 0; t < 2; ++t) {
      const int f = tid + t * 256;
      const int rr = f >> 5, c4 = (f & 31) << 2;
      *reinterpret_cast<float4*>(&hl[rr][c4]) = ld4(&hsyn[(size_t)(b0 + rr) * H_DIM + i0 + c4]);
    }
    __syncthreads();
    {
      float4 u0 = *reinterpret_cast<float4*>(&hl[r][c * 8]);
      float4 u1 = *reinterpret_cast<float4*>(&hl[r][c * 8 + 4]);
      ss += u0.x*u0.x + u0.y*u0.y + u0.z*u0.z + u0.w*u0.w
          + u1.x*u1.x + u1.y*u1.y + u1.z*u1.z + u1.w*u1.w;
    }
#pragma unroll 8
    for (int i = 0; i < 128; i += 4) {
      float4 a = *reinterpret_cast<float4*>(&hl[r][i]);
#pragma unroll
      for (int m = 0; m < 4; ++m) {
        float4 p = *reinterpret_cast<float4*>(&pl[c + 16 * m][i]);
        float s = sim[m];
        s = fmaf(a.x, p.x, s); s = fmaf(a.y, p.y, s);
        s = fmaf(a.z, p.z, s); s = fmaf(a.w, p.w, s);
        sim[m] = s;
      }
    }
  }

  // reduce sumsq across the 16 lanes owning this row
  for (int o = 1; o < 16; o <<= 1) ss += __shfl_xor(ss, o);
  const float rninv = 1.0f / fmaxf(sqrtf(ss), 1e-12f);

  float g[4];
#pragma unroll
  for (int m = 0; m < 4; ++m) g[m] = sim[m] * rninv * gates[c + 16 * m];

  // softmax over 64 (max-subtracted, like jax.nn.softmax)
  float mx = fmaxf(fmaxf(g[0], g[1]), fmaxf(g[2], g[3]));
  for (int o = 1; o < 16; o <<= 1) mx = fmaxf(mx, __shfl_xor(mx, o));
  float e[4], Z = 0.f;
#pragma unroll
  for (int m = 0; m < 4; ++m) { e[m] = expf(g[m] - mx); Z += e[m]; }
  for (int o = 1; o < 16; o <<= 1) Z += __shfl_xor(Z, o);
  const float invZ = 1.0f / Z;
  float w[4];
#pragma unroll
  for (int m = 0; m < 4; ++m) w[m] = e[m] * invZ;

  // entropy: ent_row = -sum w*log(w+1e-8); accumulate mean
  float es = 0.f;
#pragma unroll
  for (int m = 0; m < 4; ++m) es += w[m] * logf(w[m] + 1e-8f);
  for (int o = 1; o < 16; o <<= 1) es += __shfl_xor(es, o);

  // argmax with first-index tie-break (matches np.argmax)
  float bv = w[0]; int bi = c;
#pragma unroll
  for (int m = 1; m < 4; ++m) {
    if (w[m] > bv) { bv = w[m]; bi = c + 16 * m; }
  }
  for (int o = 1; o < 16; o <<= 1) {
    float ov = __shfl_xor(bv, o);
    int oi = __shfl_xor(bi, o);
    if (ov > bv || (ov == bv && oi < bi)) { bv = ov; bi = oi; }
  }
  if (c == 0) {
    atomicAdd(entSlot, -es * (1.0f / (float)B_ROWS));
    outPid[b0 + r] = (float)bi;
  }

  // action = w @ actions
  wl[r][c] = w[0]; wl[r][c + 16] = w[1]; wl[r][c + 32] = w[2]; wl[r][c + 48] = w[3];
  __syncthreads();
  float accv[4] = {0.f, 0.f, 0.f, 0.f};
#pragma unroll 16
  for (int k = 0; k < 64; ++k) {
    const float wv = wl[r][k];
    accv[0] = fmaf(wv, al[k][c], accv[0]);
    accv[1] = fmaf(wv, al[k][c + 16], accv[1]);
    accv[2] = fmaf(wv, al[k][c + 32], accv[2]);
    accv[3] = fmaf(wv, al[k][c + 48], accv[3]);
  }
  const size_t ob = (size_t)(b0 + r) * 64;
  outAct[ob + c]      = accv[0];
  outAct[ob + c + 16] = accv[1];
  outAct[ob + c + 32] = accv[2];
  outAct[ob + c + 48] = accv[3];
}

extern "C" void kernel_launch(void* const* d_in, const int* in_sizes, int n_in,
                              void* d_out, int out_size, void* d_ws, size_t ws_size,
                              hipStream_t stream) {
  (void)in_sizes; (void)n_in; (void)out_size; (void)ws_size;
  const float* h       = (const float*)d_in[0];
  const float* projW   = (const float*)d_in[1];
  const float* synW    = (const float*)d_in[2];
  const float* mask    = (const float*)d_in[3];
  const float* protos  = (const float*)d_in[4];
  const float* actions = (const float*)d_in[5];
  const float* gates   = (const float*)d_in[6];
  float* out = (float*)d_out;

  // workspace layout (floats): Mc[2048*2048] | hsyn[8192*2048] | pn[64*2048]  (~84.4 MB)
  float* Mc   = (float*)d_ws;
  float* hsyn = Mc + (size_t)H_DIM * H_DIM;
  float* pn   = hsyn + (size_t)B_ROWS * H_DIM;

  proto_norm_kernel<<<64, 256, 0, stream>>>(protos, pn);
  // Mc = projW^T @ (synW .* mask): C[i][j] = sum_o projW[o][i]*synW[o][j]*mask[o][j]
  sgemm128<true, true><<<dim3(16, 16), 256, 0, stream>>>(projW, synW, mask, Mc,
                                                         H_DIM, H_DIM, H_DIM, H_DIM);
  // hsyn = h @ Mc
  sgemm128<false, false><<<dim3(16, 64), 256, 0, stream>>>(h, Mc, nullptr, hsyn,
                                                           B_ROWS, H_DIM, H_DIM, H_DIM);
  hipMemsetAsync(out + 524288, 0, sizeof(float), stream);
  tail_kernel<<<512, 256, 0, stream>>>(hsyn, pn, gates, actions,
                                       out, out + 524288, out + 524289);
}

// Round 2
// 464.589 us; speedup vs baseline: 2.4226x; 2.4226x over previous
//
#include <hip/hip_runtime.h>
#include <cstdint>

#define H_DIM 2048
#define B_ROWS 8192

typedef __attribute__((ext_vector_type(8))) short bf16x8;
typedef __attribute__((ext_vector_type(4))) float f32x4;
typedef __attribute__((ext_vector_type(4))) unsigned short u16x4;

static __device__ __forceinline__ float4 ld4(const float* p) {
  return *reinterpret_cast<const float4*>(p);
}

// round-to-nearest-even fp32 -> bf16 (as raw ushort)
static __device__ __forceinline__ unsigned short f2bf(float x) {
  uint32_t b = __builtin_bit_cast(uint32_t, x);
  b += 0x7FFFu + ((b >> 16) & 1u);
  return (unsigned short)(b >> 16);
}
static __device__ __forceinline__ float bf2f(unsigned short h) {
  uint32_t b = ((uint32_t)h) << 16;
  return __builtin_bit_cast(float, b);
}

// ---------------- split h (fp32 -> hi/lo bf16) ----------------
__global__ __launch_bounds__(256) void split_kernel(const float* __restrict__ x,
                                                    unsigned short* __restrict__ hi,
                                                    unsigned short* __restrict__ lo,
                                                    int n4) {
  int i = blockIdx.x * 256 + threadIdx.x;
  const int stride = gridDim.x * 256;
  for (; i < n4; i += stride) {
    float4 v = ld4(x + (size_t)i * 4);
    u16x4 h, lw;
    unsigned short t;
    t = f2bf(v.x); h[0] = t; lw[0] = f2bf(v.x - bf2f(t));
    t = f2bf(v.y); h[1] = t; lw[1] = f2bf(v.y - bf2f(t));
    t = f2bf(v.z); h[2] = t; lw[2] = f2bf(v.z - bf2f(t));
    t = f2bf(v.w); h[3] = t; lw[3] = f2bf(v.w - bf2f(t));
    *reinterpret_cast<u16x4*>(hi + (size_t)i * 4) = h;
    *reinterpret_cast<u16x4*>(lo + (size_t)i * 4) = lw;
  }
}

// ---------------- K1: normalize protos ----------------
__global__ __launch_bounds__(256) void proto_norm_kernel(const float* __restrict__ protos,
                                                         float* __restrict__ pn) {
  const int k = blockIdx.x;
  const int tid = threadIdx.x;
  const float* row = protos + (size_t)k * H_DIM;
  float4 v0 = ld4(row + tid * 8);
  float4 v1 = ld4(row + tid * 8 + 4);
  float ss = v0.x*v0.x + v0.y*v0.y + v0.z*v0.z + v0.w*v0.w
           + v1.x*v1.x + v1.y*v1.y + v1.z*v1.z + v1.w*v1.w;
  for (int o = 32; o > 0; o >>= 1) ss += __shfl_down(ss, o);
  __shared__ float red[4];
  const int lane = tid & 63, wv = tid >> 6;
  if (lane == 0) red[wv] = ss;
  __syncthreads();
  const float tot = red[0] + red[1] + red[2] + red[3];
  const float inv = 1.0f / fmaxf(sqrtf(tot), 1e-12f);
  float* orow = pn + (size_t)k * H_DIM;
  *reinterpret_cast<float4*>(orow + tid*8)     = make_float4(v0.x*inv, v0.y*inv, v0.z*inv, v0.w*inv);
  *reinterpret_cast<float4*>(orow + tid*8 + 4) = make_float4(v1.x*inv, v1.y*inv, v1.z*inv, v1.w*inv);
}

// ---------------- shared split-bf16 MFMA core ----------------
// LDS tiles: [128 rows][32 k] bf16, 16B blocks swizzled: data k-octet db stored at
// slot s = db ^ (j&3) ^ ((j>>2)&3). Frag read: lane l -> row j = wrow + mi*16 + (l&15),
// k-octet l>>4. 64 lanes tile 1KB contiguously per read -> conflict-free.
static __device__ __forceinline__ void mfma_core(const unsigned short* sAh, const unsigned short* sAl,
                                                 const unsigned short* sBh, const unsigned short* sBl,
                                                 int l, int wm, int wn, f32x4 acc[4][4]) {
  bf16x8 ah[4], al[4], bh[4], bl[4];
#pragma unroll
  for (int mi = 0; mi < 4; ++mi) {
    const int j = wm * 64 + mi * 16 + (l & 15);
    const int blk = (l >> 4) ^ (j & 3) ^ ((j >> 2) & 3);
    ah[mi] = *reinterpret_cast<const bf16x8*>(sAh + j * 32 + blk * 8);
    al[mi] = *reinterpret_cast<const bf16x8*>(sAl + j * 32 + blk * 8);
  }
#pragma unroll
  for (int ni = 0; ni < 4; ++ni) {
    const int j = wn * 64 + ni * 16 + (l & 15);
    const int blk = (l >> 4) ^ (j & 3) ^ ((j >> 2) & 3);
    bh[ni] = *reinterpret_cast<const bf16x8*>(sBh + j * 32 + blk * 8);
    bl[ni] = *reinterpret_cast<const bf16x8*>(sBl + j * 32 + blk * 8);
  }
#pragma unroll
  for (int mi = 0; mi < 4; ++mi)
#pragma unroll
    for (int ni = 0; ni < 4; ++ni) {
      acc[mi][ni] = __builtin_amdgcn_mfma_f32_16x16x32_bf16(ah[mi], bh[ni], acc[mi][ni], 0, 0, 0);
      acc[mi][ni] = __builtin_amdgcn_mfma_f32_16x16x32_bf16(ah[mi], bl[ni], acc[mi][ni], 0, 0, 0);
      acc[mi][ni] = __builtin_amdgcn_mfma_f32_16x16x32_bf16(al[mi], bh[ni], acc[mi][ni], 0, 0, 0);
    }
}

// ---------------- K2: GEMM-M  Mt[j][i] = sum_o (synW*mask)[o][j] * projW[o][i] ----------------
// transposed reg-staging (fp32 global -> hi/lo bf16 swizzled LDS), MFMA core, bf16 hi/lo output
__global__ __launch_bounds__(256, 2) void gemmM_kernel(const float* __restrict__ synW,
                                                       const float* __restrict__ mask,
                                                       const float* __restrict__ projW,
                                                       unsigned short* __restrict__ mtHi,
                                                       unsigned short* __restrict__ mtLo) {
  __shared__ unsigned short lds[4 * 4096];
  unsigned short* sAh = lds;
  unsigned short* sAl = lds + 4096;
  unsigned short* sBh = lds + 8192;
  unsigned short* sBl = lds + 12288;
  const int tid = threadIdx.x;
  const int l = tid & 63, w = tid >> 6;
  const int bid = blockIdx.x;
  const int wg = (bid & 7) * 32 + (bid >> 3);     // xcd swizzle (256 % 8 == 0)
  const int j0 = (wg >> 4) * 128, i0 = (wg & 15) * 128;
  const int wm = w >> 1, wn = w & 1;

  const int jj = tid & 127;   // tile-local staged row
  const int oh = tid >> 7;    // o half (0: q=0..15 -> octets 0,1 ; 1: octets 2,3)
  const int swzJ = (jj & 3) ^ ((jj >> 2) & 3);
  const int s0 = (oh * 2) ^ swzJ, s1 = (oh * 2 + 1) ^ swzJ;

  f32x4 acc[4][4];
#pragma unroll
  for (int mi = 0; mi < 4; ++mi)
#pragma unroll
    for (int ni = 0; ni < 4; ++ni) acc[mi][ni] = (f32x4){0.f, 0.f, 0.f, 0.f};

  for (int o0 = 0; o0 < H_DIM; o0 += 32) {
    float av[16], bv[16];
#pragma unroll
    for (int q = 0; q < 16; ++q) {
      const size_t ro = (size_t)(o0 + oh * 16 + q) * H_DIM;
      av[q] = synW[ro + j0 + jj] * mask[ro + j0 + jj];
      bv[q] = projW[ro + i0 + jj];
    }
    bf16x8 vAh0, vAh1, vAl0, vAl1, vBh0, vBh1, vBl0, vBl1;
#pragma unroll
    for (int q = 0; q < 8; ++q) {
      unsigned short t;
      t = f2bf(av[q]);     vAh0[q] = (short)t; vAl0[q] = (short)f2bf(av[q] - bf2f(t));
      t = f2bf(av[q + 8]); vAh1[q] = (short)t; vAl1[q] = (short)f2bf(av[q + 8] - bf2f(t));
      t = f2bf(bv[q]);     vBh0[q] = (short)t; vBl0[q] = (short)f2bf(bv[q] - bf2f(t));
      t = f2bf(bv[q + 8]); vBh1[q] = (short)t; vBl1[q] = (short)f2bf(bv[q + 8] - bf2f(t));
    }
    __syncthreads();   // previous iteration's frag reads complete
    *reinterpret_cast<bf16x8*>(sAh + jj * 32 + s0 * 8) = vAh0;
    *reinterpret_cast<bf16x8*>(sAh + jj * 32 + s1 * 8) = vAh1;
    *reinterpret_cast<bf16x8*>(sAl + jj * 32 + s0 * 8) = vAl0;
    *reinterpret_cast<bf16x8*>(sAl + jj * 32 + s1 * 8) = vAl1;
    *reinterpret_cast<bf16x8*>(sBh + jj * 32 + s0 * 8) = vBh0;
    *reinterpret_cast<bf16x8*>(sBh + jj * 32 + s1 * 8) = vBh1;
    *reinterpret_cast<bf16x8*>(sBl + jj * 32 + s0 * 8) = vBl0;
    *reinterpret_cast<bf16x8*>(sBl + jj * 32 + s1 * 8) = vBl1;
    __syncthreads();
    mfma_core(sAh, sAl, sBh, sBl, l, wm, wn, acc);
  }

  const int r0 = (l >> 4) * 4, cc = l & 15;
#pragma unroll
  for (int mi = 0; mi < 4; ++mi)
#pragma unroll
    for (int ni = 0; ni < 4; ++ni)
#pragma unroll
      for (int r = 0; r < 4; ++r) {
        const float v = acc[mi][ni][r];
        const size_t idx = (size_t)(j0 + wm * 64 + mi * 16 + r0 + r) * H_DIM
                         + i0 + wn * 64 + ni * 16 + cc;
        const unsigned short hv = f2bf(v);
        mtHi[idx] = hv;
        mtLo[idx] = f2bf(v - bf2f(hv));
      }
}

// ---------------- K3: GEMM-H  hsyn[m][n] = sum_k h[m][k] * Mt[n][k] ----------------
// split-bf16 operands pre-staged in global; global_load_lds(16B) staging, pre-swizzled source
__global__ __launch_bounds__(256, 2) void gemmH_kernel(const unsigned short* __restrict__ aHi,
                                                       const unsigned short* __restrict__ aLo,
                                                       const unsigned short* __restrict__ bHi,
                                                       const unsigned short* __restrict__ bLo,
                                                       float* __restrict__ C) {
  __shared__ unsigned short lds[4 * 4096];
  const int tid = threadIdx.x;
  const int l = tid & 63, w = tid >> 6;
  const int bid = blockIdx.x;
  const int wg = (bid & 7) * 128 + (bid >> 3);    // xcd swizzle (1024 % 8 == 0)
  const int m0 = (wg >> 4) * 128, n0 = (wg & 15) * 128;
  const int wm = w >> 1, wn = w & 1;

  f32x4 acc[4][4];
#pragma unroll
  for (int mi = 0; mi < 4; ++mi)
#pragma unroll
    for (int ni = 0; ni < 4; ++ni) acc[mi][ni] = (f32x4){0.f, 0.f, 0.f, 0.f};

  // wave w stages tile w: 0=Ahi 1=Alo 2=Bhi 3=Blo
  const unsigned short* src = (w == 0) ? aHi : (w == 1) ? aLo : (w == 2) ? bHi : bLo;
  const int row0 = (w < 2) ? m0 : n0;
  unsigned short* dst = lds + w * 4096;
  const int jl = l >> 2;

  for (int k0 = 0; k0 < H_DIM; k0 += 32) {
#pragma unroll
    for (int i = 0; i < 8; ++i) {
      const int j = i * 16 + jl;
      const int b = (l & 3) ^ (j & 3) ^ ((j >> 2) & 3);   // data octet for dest slot (l&3)
      const unsigned short* g = src + (size_t)(row0 + j) * H_DIM + k0 + b * 8;
      __builtin_amdgcn_global_load_lds((const __attribute__((address_space(1))) void*)g,
                                       (__attribute__((address_space(3))) void*)(dst + i * 512),
                                       16, 0, 0);
    }
    __syncthreads();
    mfma_core(lds, lds + 4096, lds + 8192, lds + 12288, l, wm, wn, acc);
    __syncthreads();
  }

  const int r0 = (l >> 4) * 4, cc = l & 15;
#pragma unroll
  for (int mi = 0; mi < 4; ++mi)
#pragma unroll
    for (int ni = 0; ni < 4; ++ni)
#pragma unroll
      for (int r = 0; r < 4; ++r)
        C[(size_t)(m0 + wm * 64 + mi * 16 + r0 + r) * H_DIM + n0 + wn * 64 + ni * 16 + cc] =
            acc[mi][ni][r];
}

// ---------------- K4: fused norm + sim + softmax + entropy + argmax + action ----------------
__global__ __launch_bounds__(256) void tail_kernel(const float* __restrict__ hsyn,
                                                   const float* __restrict__ pn,
                                                   const float* __restrict__ gates,
                                                   const float* __restrict__ actions,
                                                   float* __restrict__ outAct,
                                                   float* __restrict__ entSlot,
                                                   float* __restrict__ outPid) {
  __shared__ float pl[64][132];
  __shared__ float hl[16][132];
  __shared__ float al[64][68];
  __shared__ float wl[16][68];
  const int tid = threadIdx.x;
  const int c = tid & 15, r = tid >> 4;
  const int b0 = blockIdx.x * 16;

#pragma unroll
  for (int t = 0; t < 4; ++t) {
    const int f = tid + t * 256;
    const int k = f >> 4, c4 = (f & 15) << 2;
    *reinterpret_cast<float4*>(&al[k][c4]) = ld4(&actions[k * 64 + c4]);
  }

  float sim[4] = {0.f, 0.f, 0.f, 0.f};
  float ss = 0.f;

  for (int i0 = 0; i0 < H_DIM; i0 += 128) {
    __syncthreads();
#pragma unroll
    for (int t = 0; t < 8; ++t) {
      const int f = tid + t * 256;
      const int k = f >> 5, c4 = (f & 31) << 2;
      *reinterpret_cast<float4*>(&pl[k][c4]) = ld4(&pn[(size_t)k * H_DIM + i0 + c4]);
    }
#pragma unroll
    for (int t = 0; t < 2; ++t) {
      const int f = tid + t * 256;
      const int rr = f >> 5, c4 = (f & 31) << 2;
      *reinterpret_cast<float4*>(&hl[rr][c4]) = ld4(&hsyn[(size_t)(b0 + rr) * H_DIM + i0 + c4]);
    }
    __syncthreads();
    {
      float4 u0 = *reinterpret_cast<float4*>(&hl[r][c * 8]);
      float4 u1 = *reinterpret_cast<float4*>(&hl[r][c * 8 + 4]);
      ss += u0.x*u0.x + u0.y*u0.y + u0.z*u0.z + u0.w*u0.w
          + u1.x*u1.x + u1.y*u1.y + u1.z*u1.z + u1.w*u1.w;
    }
#pragma unroll 8
    for (int i = 0; i < 128; i += 4) {
      float4 a = *reinterpret_cast<float4*>(&hl[r][i]);
#pragma unroll
      for (int m = 0; m < 4; ++m) {
        float4 p = *reinterpret_cast<float4*>(&pl[c + 16 * m][i]);
        float s = sim[m];
        s = fmaf(a.x, p.x, s); s = fmaf(a.y, p.y, s);
        s = fmaf(a.z, p.z, s); s = fmaf(a.w, p.w, s);
        sim[m] = s;
      }
    }
  }

  for (int o = 1; o < 16; o <<= 1) ss += __shfl_xor(ss, o);
  const float rninv = 1.0f / fmaxf(sqrtf(ss), 1e-12f);

  float g[4];
#pragma unroll
  for (int m = 0; m < 4; ++m) g[m] = sim[m] * rninv * gates[c + 16 * m];

  float mx = fmaxf(fmaxf(g[0], g[1]), fmaxf(g[2], g[3]));
  for (int o = 1; o < 16; o <<= 1) mx = fmaxf(mx, __shfl_xor(mx, o));
  float e[4], Z = 0.f;
#pragma unroll
  for (int m = 0; m < 4; ++m) { e[m] = expf(g[m] - mx); Z += e[m]; }
  for (int o = 1; o < 16; o <<= 1) Z += __shfl_xor(Z, o);
  const float invZ = 1.0f / Z;
  float wgt[4];
#pragma unroll
  for (int m = 0; m < 4; ++m) wgt[m] = e[m] * invZ;

  float es = 0.f;
#pragma unroll
  for (int m = 0; m < 4; ++m) es += wgt[m] * logf(wgt[m] + 1e-8f);
  for (int o = 1; o < 16; o <<= 1) es += __shfl_xor(es, o);

  float bv = wgt[0]; int bi = c;
#pragma unroll
  for (int m = 1; m < 4; ++m) {
    if (wgt[m] > bv) { bv = wgt[m]; bi = c + 16 * m; }
  }
  for (int o = 1; o < 16; o <<= 1) {
    float ov = __shfl_xor(bv, o);
    int oi = __shfl_xor(bi, o);
    if (ov > bv || (ov == bv && oi < bi)) { bv = ov; bi = oi; }
  }
  if (c == 0) {
    atomicAdd(entSlot, -es * (1.0f / (float)B_ROWS));
    outPid[b0 + r] = (float)bi;
  }

  wl[r][c] = wgt[0]; wl[r][c + 16] = wgt[1]; wl[r][c + 32] = wgt[2]; wl[r][c + 48] = wgt[3];
  __syncthreads();
  float accv[4] = {0.f, 0.f, 0.f, 0.f};
#pragma unroll 16
  for (int k = 0; k < 64; ++k) {
    const float wv = wl[r][k];
    accv[0] = fmaf(wv, al[k][c], accv[0]);
    accv[1] = fmaf(wv, al[k][c + 16], accv[1]);
    accv[2] = fmaf(wv, al[k][c + 32], accv[2]);
    accv[3] = fmaf(wv, al[k][c + 48], accv[3]);
  }
  const size_t ob = (size_t)(b0 + r) * 64;
  outAct[ob + c]      = accv[0];
  outAct[ob + c + 16] = accv[1];
  outAct[ob + c + 32] = accv[2];
  outAct[ob + c + 48] = accv[3];
}

extern "C" void kernel_launch(void* const* d_in, const int* in_sizes, int n_in,
                              void* d_out, int out_size, void* d_ws, size_t ws_size,
                              hipStream_t stream) {
  (void)in_sizes; (void)n_in; (void)out_size; (void)ws_size;
  const float* h       = (const float*)d_in[0];
  const float* projW   = (const float*)d_in[1];
  const float* synW    = (const float*)d_in[2];
  const float* mask    = (const float*)d_in[3];
  const float* protos  = (const float*)d_in[4];
  const float* actions = (const float*)d_in[5];
  const float* gates   = (const float*)d_in[6];
  float* out = (float*)d_out;

  // ws layout: hsyn f32 (64MB) | hHi bf16 (32MB) | hLo (32MB) | mtHi (8MB) | mtLo (8MB) | pn f32 (0.5MB)
  float* hsyn = (float*)d_ws;
  unsigned short* hHi = (unsigned short*)(hsyn + (size_t)B_ROWS * H_DIM);
  unsigned short* hLo = hHi + (size_t)B_ROWS * H_DIM;
  unsigned short* mtHi = hLo + (size_t)B_ROWS * H_DIM;
  unsigned short* mtLo = mtHi + (size_t)H_DIM * H_DIM;
  float* pn = (float*)(mtLo + (size_t)H_DIM * H_DIM);

  split_kernel<<<2048, 256, 0, stream>>>(h, hHi, hLo, (B_ROWS * H_DIM) / 4);
  proto_norm_kernel<<<64, 256, 0, stream>>>(protos, pn);
  gemmM_kernel<<<256, 256, 0, stream>>>(synW, mask, projW, mtHi, mtLo);
  gemmH_kernel<<<1024, 256, 0, stream>>>(hHi, hLo, mtHi, mtLo, hsyn);
  hipMemsetAsync(out + 524288, 0, sizeof(float), stream);
  tail_kernel<<<512, 256, 0, stream>>>(hsyn, pn, gates, actions,
                                       out, out + 524288, out + 524289);
}

// Round 3
// 284.175 us; speedup vs baseline: 3.9606x; 1.6349x over previous
//
#include <hip/hip_runtime.h>
#include <cstdint>

#define H_DIM 2048
#define B_ROWS 8192

typedef __attribute__((ext_vector_type(8))) short bf16x8;
typedef __attribute__((ext_vector_type(4))) float f32x4;
typedef __attribute__((ext_vector_type(4))) unsigned short u16x4;

static __device__ __forceinline__ float4 ld4(const float* p) {
  return *reinterpret_cast<const float4*>(p);
}

// round-to-nearest-even fp32 -> bf16 (raw ushort)
static __device__ __forceinline__ unsigned short f2bf(float x) {
  uint32_t b = __builtin_bit_cast(uint32_t, x);
  b += 0x7FFFu + ((b >> 16) & 1u);
  return (unsigned short)(b >> 16);
}
static __device__ __forceinline__ float bf2f(unsigned short h) {
  uint32_t b = ((uint32_t)h) << 16;
  return __builtin_bit_cast(float, b);
}

// MFMA fragment read from swizzled [rows][32-k] bf16 LDS tile.
// 16B octet of data-k-index (l>>4) for row stored at slot (l>>4)^(row&3)^((row>>2)&3).
static __device__ __forceinline__ bf16x8 fragld(const unsigned short* s, int row, int l) {
  const int blk = (l >> 4) ^ (row & 3) ^ ((row >> 2) & 3);
  return *reinterpret_cast<const bf16x8*>(s + row * 32 + blk * 8);
}

// ---------------- split h (fp32 -> hi/lo bf16) ----------------
__global__ __launch_bounds__(256) void split_kernel(const float* __restrict__ x,
                                                    unsigned short* __restrict__ hi,
                                                    unsigned short* __restrict__ lo,
                                                    int n4) {
  int i = blockIdx.x * 256 + threadIdx.x;
  const int stride = gridDim.x * 256;
  for (; i < n4; i += stride) {
    float4 v = ld4(x + (size_t)i * 4);
    u16x4 h, lw;
    unsigned short t;
    t = f2bf(v.x); h[0] = t; lw[0] = f2bf(v.x - bf2f(t));
    t = f2bf(v.y); h[1] = t; lw[1] = f2bf(v.y - bf2f(t));
    t = f2bf(v.z); h[2] = t; lw[2] = f2bf(v.z - bf2f(t));
    t = f2bf(v.w); h[3] = t; lw[3] = f2bf(v.w - bf2f(t));
    *reinterpret_cast<u16x4*>(hi + (size_t)i * 4) = h;
    *reinterpret_cast<u16x4*>(lo + (size_t)i * 4) = lw;
  }
}

// ---------------- normalize protos ----------------
__global__ __launch_bounds__(256) void proto_norm_kernel(const float* __restrict__ protos,
                                                         float* __restrict__ pn) {
  const int k = blockIdx.x;
  const int tid = threadIdx.x;
  const float* row = protos + (size_t)k * H_DIM;
  float4 v0 = ld4(row + tid * 8);
  float4 v1 = ld4(row + tid * 8 + 4);
  float ss = v0.x*v0.x + v0.y*v0.y + v0.z*v0.z + v0.w*v0.w
           + v1.x*v1.x + v1.y*v1.y + v1.z*v1.z + v1.w*v1.w;
  for (int o = 32; o > 0; o >>= 1) ss += __shfl_down(ss, o);
  __shared__ float red[4];
  const int lane = tid & 63, wv = tid >> 6;
  if (lane == 0) red[wv] = ss;
  __syncthreads();
  const float tot = red[0] + red[1] + red[2] + red[3];
  const float inv = 1.0f / fmaxf(sqrtf(tot), 1e-12f);
  float* orow = pn + (size_t)k * H_DIM;
  *reinterpret_cast<float4*>(orow + tid*8)     = make_float4(v0.x*inv, v0.y*inv, v0.z*inv, v0.w*inv);
  *reinterpret_cast<float4*>(orow + tid*8 + 4) = make_float4(v1.x*inv, v1.y*inv, v1.z*inv, v1.w*inv);
}

// ---------------- gemmT: TP[os][o][p] = sum_{j in split} synWm[o][j]*pn[p][j] ----------------
// 128x64 tile, 4-product split-bf16, K-split 8. grid 128 = 16 o-tiles x 8 splits.
__global__ __launch_bounds__(256, 2) void gemmT_kernel(const float* __restrict__ synW,
                                                       const float* __restrict__ mask,
                                                       const float* __restrict__ pn,
                                                       float* __restrict__ TP) {
  __shared__ unsigned short sAh[4096], sAl[4096], sBh[2048], sBl[2048];
  const int tid = threadIdx.x;
  const int l = tid & 63, w = tid >> 6;
  const int ot = blockIdx.x >> 3, os = blockIdx.x & 7;
  const int o0 = ot * 128;

  f32x4 acc[2][4];
#pragma unroll
  for (int mi = 0; mi < 2; ++mi)
#pragma unroll
    for (int ni = 0; ni < 4; ++ni) acc[mi][ni] = (f32x4){0.f, 0.f, 0.f, 0.f};

  const int rA0 = tid >> 2, ocA0 = tid & 3;          // t=0: octet (rA0, ocA0)
  const int rA1 = (tid + 256) >> 2, ocA1 = tid & 3;  // t=1
  const int kB = tid >> 2, ocB = tid & 3;

  for (int it = 0; it < 8; ++it) {
    const int j0 = os * 256 + it * 32;
    // A octets (2 per thread): synW*mask rows o0+r, 8 floats at j0+oc*8
    bf16x8 aH[2], aL[2];
    int rr[2] = {rA0, rA1};
#pragma unroll
    for (int t = 0; t < 2; ++t) {
      const float* ps = synW + (size_t)(o0 + rr[t]) * H_DIM + j0 + ocA0 * 8;
      const float* pm = mask + (size_t)(o0 + rr[t]) * H_DIM + j0 + ocA0 * 8;
#pragma unroll
      for (int q = 0; q < 8; ++q) {
        float v = ps[q] * pm[q];
        unsigned short hv = f2bf(v);
        aH[t][q] = (short)hv; aL[t][q] = (short)f2bf(v - bf2f(hv));
      }
    }
    // B octet (1 per thread): pn row kB
    bf16x8 bH, bL;
    {
      const float* pp = pn + (size_t)kB * H_DIM + j0 + ocB * 8;
#pragma unroll
      for (int q = 0; q < 8; ++q) {
        float v = pp[q];
        unsigned short hv = f2bf(v);
        bH[q] = (short)hv; bL[q] = (short)f2bf(v - bf2f(hv));
      }
    }
    __syncthreads();
    {
      const int s0 = ocA0 ^ (rA0 & 3) ^ ((rA0 >> 2) & 3);
      const int s1 = ocA1 ^ (rA1 & 3) ^ ((rA1 >> 2) & 3);
      *reinterpret_cast<bf16x8*>(sAh + rA0 * 32 + s0 * 8) = aH[0];
      *reinterpret_cast<bf16x8*>(sAl + rA0 * 32 + s0 * 8) = aL[0];
      *reinterpret_cast<bf16x8*>(sAh + rA1 * 32 + s1 * 8) = aH[1];
      *reinterpret_cast<bf16x8*>(sAl + rA1 * 32 + s1 * 8) = aL[1];
      const int sb = ocB ^ (kB & 3) ^ ((kB >> 2) & 3);
      *reinterpret_cast<bf16x8*>(sBh + kB * 32 + sb * 8) = bH;
      *reinterpret_cast<bf16x8*>(sBl + kB * 32 + sb * 8) = bL;
    }
    __syncthreads();
    bf16x8 ah[2], al[2], bh[4], bl[4];
#pragma unroll
    for (int mi = 0; mi < 2; ++mi) {
      const int j = w * 32 + mi * 16 + (l & 15);
      ah[mi] = fragld(sAh, j, l); al[mi] = fragld(sAl, j, l);
    }
#pragma unroll
    for (int ni = 0; ni < 4; ++ni) {
      const int j = ni * 16 + (l & 15);
      bh[ni] = fragld(sBh, j, l); bl[ni] = fragld(sBl, j, l);
    }
#pragma unroll
    for (int mi = 0; mi < 2; ++mi)
#pragma unroll
      for (int ni = 0; ni < 4; ++ni) {
        acc[mi][ni] = __builtin_amdgcn_mfma_f32_16x16x32_bf16(ah[mi], bh[ni], acc[mi][ni], 0, 0, 0);
        acc[mi][ni] = __builtin_amdgcn_mfma_f32_16x16x32_bf16(ah[mi], bl[ni], acc[mi][ni], 0, 0, 0);
        acc[mi][ni] = __builtin_amdgcn_mfma_f32_16x16x32_bf16(al[mi], bh[ni], acc[mi][ni], 0, 0, 0);
        acc[mi][ni] = __builtin_amdgcn_mfma_f32_16x16x32_bf16(al[mi], bl[ni], acc[mi][ni], 0, 0, 0);
      }
  }
  const int r0 = (l >> 4) * 4, cc = l & 15;
#pragma unroll
  for (int mi = 0; mi < 2; ++mi)
#pragma unroll
    for (int ni = 0; ni < 4; ++ni)
#pragma unroll
      for (int r = 0; r < 4; ++r)
        TP[((size_t)os * H_DIM + o0 + w * 32 + mi * 16 + r0 + r) * 64 + ni * 16 + cc] =
            acc[mi][ni][r];
}

// ---------------- reduceTR: P[8][2048][64] -> dHi/dLo[64][2048] (sum splits, transpose, bf16-split) ----------------
__global__ __launch_bounds__(256) void reduceTR_kernel(const float* __restrict__ P,
                                                       unsigned short* __restrict__ dHi,
                                                       unsigned short* __restrict__ dLo) {
  __shared__ float lt[64][65];
  const int tid = threadIdx.x;
  const int a0 = blockIdx.x * 64;
  const int al = tid >> 2, b0 = (tid & 3) * 16;
  f32x4 a4[4];
#pragma unroll
  for (int q = 0; q < 4; ++q) a4[q] = (f32x4){0.f, 0.f, 0.f, 0.f};
  for (int s = 0; s < 8; ++s) {
    const float* p = P + ((size_t)s * H_DIM + a0 + al) * 64 + b0;
#pragma unroll
    for (int q = 0; q < 4; ++q) {
      f32x4 v = *reinterpret_cast<const f32x4*>(p + q * 4);
      a4[q] += v;
    }
  }
#pragma unroll
  for (int q = 0; q < 4; ++q)
#pragma unroll
    for (int e = 0; e < 4; ++e) lt[b0 + q * 4 + e][al] = a4[q][e];
  __syncthreads();
  const int b = tid >> 2, aq = (tid & 3) * 16;
  bf16x8 h0, h1, l0, l1;
#pragma unroll
  for (int j = 0; j < 8; ++j) {
    float v = lt[b][aq + j];
    unsigned short hv = f2bf(v);
    h0[j] = (short)hv; l0[j] = (short)f2bf(v - bf2f(hv));
    float v2 = lt[b][aq + 8 + j];
    unsigned short hv2 = f2bf(v2);
    h1[j] = (short)hv2; l1[j] = (short)f2bf(v2 - bf2f(hv2));
  }
  unsigned short* oh = dHi + (size_t)b * H_DIM + a0 + aq;
  unsigned short* ol = dLo + (size_t)b * H_DIM + a0 + aq;
  *reinterpret_cast<bf16x8*>(oh) = h0; *reinterpret_cast<bf16x8*>(oh + 8) = h1;
  *reinterpret_cast<bf16x8*>(ol) = l0; *reinterpret_cast<bf16x8*>(ol + 8) = l1;
}

// ---------------- gemmR: RP[os][i][p] = sum_{o in split} projW[o][i]*Tt[p][o] ----------------
// A transposed via reg-staging (fp32 -> split), B pre-split bf16. 4-product.
__global__ __launch_bounds__(256, 2) void gemmR_kernel(const float* __restrict__ projW,
                                                       const unsigned short* __restrict__ TtHi,
                                                       const unsigned short* __restrict__ TtLo,
                                                       float* __restrict__ RP) {
  __shared__ unsigned short sAh[4096], sAl[4096], sBh[2048], sBl[2048];
  const int tid = threadIdx.x;
  const int l = tid & 63, w = tid >> 6;
  const int itile = blockIdx.x >> 3, os = blockIdx.x & 7;
  const int i0 = itile * 128;
  const int jj = tid & 127, oh = tid >> 7;
  const int swzJ = (jj & 3) ^ ((jj >> 2) & 3);
  const int s0 = (oh * 2) ^ swzJ, s1 = (oh * 2 + 1) ^ swzJ;
  const int kB = tid >> 2, ocB = tid & 3;
  const int sb = ocB ^ (kB & 3) ^ ((kB >> 2) & 3);

  f32x4 acc[2][4];
#pragma unroll
  for (int mi = 0; mi < 2; ++mi)
#pragma unroll
    for (int ni = 0; ni < 4; ++ni) acc[mi][ni] = (f32x4){0.f, 0.f, 0.f, 0.f};

  for (int it = 0; it < 8; ++it) {
    const int o0 = os * 256 + it * 32;
    float av[16];
#pragma unroll
    for (int q = 0; q < 16; ++q)
      av[q] = projW[(size_t)(o0 + oh * 16 + q) * H_DIM + i0 + jj];
    bf16x8 aH0, aH1, aL0, aL1;
#pragma unroll
    for (int q = 0; q < 8; ++q) {
      unsigned short t;
      t = f2bf(av[q]);     aH0[q] = (short)t; aL0[q] = (short)f2bf(av[q] - bf2f(t));
      t = f2bf(av[q + 8]); aH1[q] = (short)t; aL1[q] = (short)f2bf(av[q + 8] - bf2f(t));
    }
    bf16x8 bH = *reinterpret_cast<const bf16x8*>(TtHi + (size_t)kB * H_DIM + o0 + ocB * 8);
    bf16x8 bL = *reinterpret_cast<const bf16x8*>(TtLo + (size_t)kB * H_DIM + o0 + ocB * 8);
    __syncthreads();
    *reinterpret_cast<bf16x8*>(sAh + jj * 32 + s0 * 8) = aH0;
    *reinterpret_cast<bf16x8*>(sAh + jj * 32 + s1 * 8) = aH1;
    *reinterpret_cast<bf16x8*>(sAl + jj * 32 + s0 * 8) = aL0;
    *reinterpret_cast<bf16x8*>(sAl + jj * 32 + s1 * 8) = aL1;
    *reinterpret_cast<bf16x8*>(sBh + kB * 32 + sb * 8) = bH;
    *reinterpret_cast<bf16x8*>(sBl + kB * 32 + sb * 8) = bL;
    __syncthreads();
    bf16x8 ah[2], al[2], bh[4], bl[4];
#pragma unroll
    for (int mi = 0; mi < 2; ++mi) {
      const int j = w * 32 + mi * 16 + (l & 15);
      ah[mi] = fragld(sAh, j, l); al[mi] = fragld(sAl, j, l);
    }
#pragma unroll
    for (int ni = 0; ni < 4; ++ni) {
      const int j = ni * 16 + (l & 15);
      bh[ni] = fragld(sBh, j, l); bl[ni] = fragld(sBl, j, l);
    }
#pragma unroll
    for (int mi = 0; mi < 2; ++mi)
#pragma unroll
      for (int ni = 0; ni < 4; ++ni) {
        acc[mi][ni] = __builtin_amdgcn_mfma_f32_16x16x32_bf16(ah[mi], bh[ni], acc[mi][ni], 0, 0, 0);
        acc[mi][ni] = __builtin_amdgcn_mfma_f32_16x16x32_bf16(ah[mi], bl[ni], acc[mi][ni], 0, 0, 0);
        acc[mi][ni] = __builtin_amdgcn_mfma_f32_16x16x32_bf16(al[mi], bh[ni], acc[mi][ni], 0, 0, 0);
        acc[mi][ni] = __builtin_amdgcn_mfma_f32_16x16x32_bf16(al[mi], bl[ni], acc[mi][ni], 0, 0, 0);
      }
  }
  const int r0 = (l >> 4) * 4, cc = l & 15;
#pragma unroll
  for (int mi = 0; mi < 2; ++mi)
#pragma unroll
    for (int ni = 0; ni < 4; ++ni)
#pragma unroll
      for (int r = 0; r < 4; ++r)
        RP[((size_t)os * H_DIM + i0 + w * 32 + mi * 16 + r0 + r) * 64 + ni * 16 + cc] =
            acc[mi][ni][r];
}

// ---------------- gemmM (single product): mtHi[n][k] = bf16( sum_o synWm[o][n]*projW[o][k] ) ----------------
__global__ __launch_bounds__(256, 2) void gemmM_kernel(const float* __restrict__ synW,
                                                       const float* __restrict__ mask,
                                                       const float* __restrict__ projW,
                                                       unsigned short* __restrict__ mtHi) {
  __shared__ unsigned short sAh[4096], sBh[4096];
  const int tid = threadIdx.x;
  const int l = tid & 63, w = tid >> 6;
  const int bid = blockIdx.x;
  const int wg = (bid & 7) * 32 + (bid >> 3);
  const int j0 = (wg >> 4) * 128, i0 = (wg & 15) * 128;
  const int wm = w >> 1, wn = w & 1;

  const int jj = tid & 127;
  const int oh = tid >> 7;
  const int swzJ = (jj & 3) ^ ((jj >> 2) & 3);
  const int s0 = (oh * 2) ^ swzJ, s1 = (oh * 2 + 1) ^ swzJ;

  f32x4 acc[4][4];
#pragma unroll
  for (int mi = 0; mi < 4; ++mi)
#pragma unroll
    for (int ni = 0; ni < 4; ++ni) acc[mi][ni] = (f32x4){0.f, 0.f, 0.f, 0.f};

  for (int o0 = 0; o0 < H_DIM; o0 += 32) {
    float av[16], bv[16];
#pragma unroll
    for (int q = 0; q < 16; ++q) {
      const size_t ro = (size_t)(o0 + oh * 16 + q) * H_DIM;
      av[q] = synW[ro + j0 + jj] * mask[ro + j0 + jj];
      bv[q] = projW[ro + i0 + jj];
    }
    bf16x8 vAh0, vAh1, vBh0, vBh1;
#pragma unroll
    for (int q = 0; q < 8; ++q) {
      vAh0[q] = (short)f2bf(av[q]);
      vAh1[q] = (short)f2bf(av[q + 8]);
      vBh0[q] = (short)f2bf(bv[q]);
      vBh1[q] = (short)f2bf(bv[q + 8]);
    }
    __syncthreads();
    *reinterpret_cast<bf16x8*>(sAh + jj * 32 + s0 * 8) = vAh0;
    *reinterpret_cast<bf16x8*>(sAh + jj * 32 + s1 * 8) = vAh1;
    *reinterpret_cast<bf16x8*>(sBh + jj * 32 + s0 * 8) = vBh0;
    *reinterpret_cast<bf16x8*>(sBh + jj * 32 + s1 * 8) = vBh1;
    __syncthreads();
    bf16x8 ah[4], bh[4];
#pragma unroll
    for (int mi = 0; mi < 4; ++mi) ah[mi] = fragld(sAh, wm * 64 + mi * 16 + (l & 15), l);
#pragma unroll
    for (int ni = 0; ni < 4; ++ni) bh[ni] = fragld(sBh, wn * 64 + ni * 16 + (l & 15), l);
#pragma unroll
    for (int mi = 0; mi < 4; ++mi)
#pragma unroll
      for (int ni = 0; ni < 4; ++ni)
        acc[mi][ni] = __builtin_amdgcn_mfma_f32_16x16x32_bf16(ah[mi], bh[ni], acc[mi][ni], 0, 0, 0);
  }
  const int r0 = (l >> 4) * 4, cc = l & 15;
#pragma unroll
  for (int mi = 0; mi < 4; ++mi)
#pragma unroll
    for (int ni = 0; ni < 4; ++ni)
#pragma unroll
      for (int r = 0; r < 4; ++r)
        mtHi[(size_t)(j0 + wm * 64 + mi * 16 + r0 + r) * H_DIM + i0 + wn * 64 + ni * 16 + cc] =
            f2bf(acc[mi][ni][r]);
}

// ---------------- normGemm: row-sumsq of (hHi @ mtHi^T-layout), no C write ----------------
// normP[row][nblk*2+wn] = sum over this block's 64-col slice of hsyn^2
__global__ __launch_bounds__(256, 2) void normGemm_kernel(const unsigned short* __restrict__ hHi,
                                                          const unsigned short* __restrict__ mtHi,
                                                          float* __restrict__ normP) {
  __shared__ unsigned short lds[8192];  // sAh[0:4096] | sBh[4096:8192]
  const int tid = threadIdx.x;
  const int l = tid & 63, w = tid >> 6;
  const int bid = blockIdx.x;
  const int wg = (bid & 7) * 128 + (bid >> 3);
  const int m0 = (wg >> 4) * 128, nblk = wg & 15, n0 = nblk * 128;
  const int wm = w >> 1, wn = w & 1;

  f32x4 acc[4][4];
#pragma unroll
  for (int mi = 0; mi < 4; ++mi)
#pragma unroll
    for (int ni = 0; ni < 4; ++ni) acc[mi][ni] = (f32x4){0.f, 0.f, 0.f, 0.f};

  const unsigned short* src = (w < 2) ? hHi : mtHi;
  const int row0 = (w < 2) ? m0 : n0;
  unsigned short* dst = lds + (w >> 1) * 4096 + (w & 1) * 2048;
  const int jl = l >> 2;

  for (int k0 = 0; k0 < H_DIM; k0 += 32) {
#pragma unroll
    for (int i = 0; i < 4; ++i) {
      const int j = (w & 1) * 64 + i * 16 + jl;
      const int b = (l & 3) ^ (j & 3) ^ ((j >> 2) & 3);
      const unsigned short* g = src + (size_t)(row0 + j) * H_DIM + k0 + b * 8;
      __builtin_amdgcn_global_load_lds((const __attribute__((address_space(1))) void*)g,
                                       (__attribute__((address_space(3))) void*)(dst + i * 512),
                                       16, 0, 0);
    }
    __syncthreads();
    bf16x8 ah[4], bh[4];
#pragma unroll
    for (int mi = 0; mi < 4; ++mi) ah[mi] = fragld(lds, wm * 64 + mi * 16 + (l & 15), l);
#pragma unroll
    for (int ni = 0; ni < 4; ++ni) bh[ni] = fragld(lds + 4096, wn * 64 + ni * 16 + (l & 15), l);
#pragma unroll
    for (int mi = 0; mi < 4; ++mi)
#pragma unroll
      for (int ni = 0; ni < 4; ++ni)
        acc[mi][ni] = __builtin_amdgcn_mfma_f32_16x16x32_bf16(ah[mi], bh[ni], acc[mi][ni], 0, 0, 0);
    __syncthreads();
  }

  const int r0q = l >> 4, cc = l & 15;
#pragma unroll
  for (int mi = 0; mi < 4; ++mi) {
    float s[4] = {0.f, 0.f, 0.f, 0.f};
#pragma unroll
    for (int ni = 0; ni < 4; ++ni)
#pragma unroll
      for (int r = 0; r < 4; ++r) s[r] += acc[mi][ni][r] * acc[mi][ni][r];
#pragma unroll
    for (int r = 0; r < 4; ++r)
      for (int o = 1; o < 16; o <<= 1) s[r] += __shfl_xor(s[r], o);
    if (cc == 0) {
#pragma unroll
      for (int r = 0; r < 4; ++r)
        normP[(size_t)(m0 + wm * 64 + mi * 16 + r0q * 4 + r) * 32 + nblk * 2 + wn] = s[r];
    }
  }
}

// ---------------- simGemm: simP[os][b][p] = sum_{k in split} h[b][k]*Rt[p][k], 4-product ----------------
__global__ __launch_bounds__(256, 2) void simGemm_kernel(const unsigned short* __restrict__ hHi,
                                                         const unsigned short* __restrict__ hLo,
                                                         const unsigned short* __restrict__ RtHi,
                                                         const unsigned short* __restrict__ RtLo,
                                                         float* __restrict__ simP) {
  __shared__ unsigned short lds[12288]; // sAh[0:4096] sAl[4096:8192] sBh[8192:10240] sBl[10240:12288]
  const int tid = threadIdx.x;
  const int l = tid & 63, w = tid >> 6;
  const int mt = blockIdx.x >> 2, os = blockIdx.x & 3;
  const int m0 = mt * 128;

  f32x4 acc[2][4];
#pragma unroll
  for (int mi = 0; mi < 2; ++mi)
#pragma unroll
    for (int ni = 0; ni < 4; ++ni) acc[mi][ni] = (f32x4){0.f, 0.f, 0.f, 0.f};

  const unsigned short* srcA = (w < 2) ? hHi : hLo;
  unsigned short* dstA = lds + (w >> 1) * 4096 + (w & 1) * 2048;
  unsigned short* dstBh = lds + 8192 + w * 512;
  unsigned short* dstBl = lds + 10240 + w * 512;
  const int jl = l >> 2;

  for (int it = 0; it < 16; ++it) {
    const int k0 = os * 512 + it * 32;
#pragma unroll
    for (int i = 0; i < 4; ++i) {
      const int j = (w & 1) * 64 + i * 16 + jl;
      const int b = (l & 3) ^ (j & 3) ^ ((j >> 2) & 3);
      const unsigned short* g = srcA + (size_t)(m0 + j) * H_DIM + k0 + b * 8;
      __builtin_amdgcn_global_load_lds((const __attribute__((address_space(1))) void*)g,
                                       (__attribute__((address_space(3))) void*)(dstA + i * 512),
                                       16, 0, 0);
    }
    {
      const int j = w * 16 + jl;
      const int b = (l & 3) ^ (j & 3) ^ ((j >> 2) & 3);
      const unsigned short* gh = RtHi + (size_t)j * H_DIM + k0 + b * 8;
      const unsigned short* gl = RtLo + (size_t)j * H_DIM + k0 + b * 8;
      __builtin_amdgcn_global_load_lds((const __attribute__((address_space(1))) void*)gh,
                                       (__attribute__((address_space(3))) void*)dstBh, 16, 0, 0);
      __builtin_amdgcn_global_load_lds((const __attribute__((address_space(1))) void*)gl,
                                       (__attribute__((address_space(3))) void*)dstBl, 16, 0, 0);
    }
    __syncthreads();
    bf16x8 ah[2], al[2], bh[4], bl[4];
#pragma unroll
    for (int mi = 0; mi < 2; ++mi) {
      const int j = w * 32 + mi * 16 + (l & 15);
      ah[mi] = fragld(lds, j, l); al[mi] = fragld(lds + 4096, j, l);
    }
#pragma unroll
    for (int ni = 0; ni < 4; ++ni) {
      const int j = ni * 16 + (l & 15);
      bh[ni] = fragld(lds + 8192, j, l); bl[ni] = fragld(lds + 10240, j, l);
    }
#pragma unroll
    for (int mi = 0; mi < 2; ++mi)
#pragma unroll
      for (int ni = 0; ni < 4; ++ni) {
        acc[mi][ni] = __builtin_amdgcn_mfma_f32_16x16x32_bf16(ah[mi], bh[ni], acc[mi][ni], 0, 0, 0);
        acc[mi][ni] = __builtin_amdgcn_mfma_f32_16x16x32_bf16(ah[mi], bl[ni], acc[mi][ni], 0, 0, 0);
        acc[mi][ni] = __builtin_amdgcn_mfma_f32_16x16x32_bf16(al[mi], bh[ni], acc[mi][ni], 0, 0, 0);
        acc[mi][ni] = __builtin_amdgcn_mfma_f32_16x16x32_bf16(al[mi], bl[ni], acc[mi][ni], 0, 0, 0);
      }
    __syncthreads();
  }
  const int r0 = (l >> 4) * 4, cc = l & 15;
#pragma unroll
  for (int mi = 0; mi < 2; ++mi)
#pragma unroll
    for (int ni = 0; ni < 4; ++ni)
#pragma unroll
      for (int r = 0; r < 4; ++r)
        simP[((size_t)os * B_ROWS + m0 + w * 32 + mi * 16 + r0 + r) * 64 + ni * 16 + cc] =
            acc[mi][ni][r];
}

// ---------------- tail: softmax + entropy + argmax + action from simP/normP ----------------
__global__ __launch_bounds__(256) void tail2_kernel(const float* __restrict__ simP,
                                                    const float* __restrict__ normP,
                                                    const float* __restrict__ gates,
                                                    const float* __restrict__ actions,
                                                    float* __restrict__ outAct,
                                                    float* __restrict__ entSlot,
                                                    float* __restrict__ outPid) {
  __shared__ float al[64][68];
  __shared__ float wl[16][68];
  const int tid = threadIdx.x;
  const int c = tid & 15, r = tid >> 4;
  const int b0 = blockIdx.x * 16;
  const int row = b0 + r;

#pragma unroll
  for (int t = 0; t < 4; ++t) {
    const int f = tid + t * 256;
    const int k = f >> 4, c4 = (f & 15) << 2;
    *reinterpret_cast<float4*>(&al[k][c4]) = ld4(&actions[k * 64 + c4]);
  }

  float sim[4];
#pragma unroll
  for (int m = 0; m < 4; ++m) {
    float s = 0.f;
#pragma unroll
    for (int os = 0; os < 4; ++os)
      s += simP[((size_t)os * B_ROWS + row) * 64 + c + 16 * m];
    sim[m] = s;
  }
  float nn = normP[(size_t)row * 32 + c] + normP[(size_t)row * 32 + c + 16];
  for (int o = 1; o < 16; o <<= 1) nn += __shfl_xor(nn, o);
  const float rninv = 1.0f / fmaxf(sqrtf(nn), 1e-12f);

  float g[4];
#pragma unroll
  for (int m = 0; m < 4; ++m) g[m] = sim[m] * rninv * gates[c + 16 * m];

  float mx = fmaxf(fmaxf(g[0], g[1]), fmaxf(g[2], g[3]));
  for (int o = 1; o < 16; o <<= 1) mx = fmaxf(mx, __shfl_xor(mx, o));
  float e[4], Z = 0.f;
#pragma unroll
  for (int m = 0; m < 4; ++m) { e[m] = expf(g[m] - mx); Z += e[m]; }
  for (int o = 1; o < 16; o <<= 1) Z += __shfl_xor(Z, o);
  const float invZ = 1.0f / Z;
  float wgt[4];
#pragma unroll
  for (int m = 0; m < 4; ++m) wgt[m] = e[m] * invZ;

  float es = 0.f;
#pragma unroll
  for (int m = 0; m < 4; ++m) es += wgt[m] * logf(wgt[m] + 1e-8f);
  for (int o = 1; o < 16; o <<= 1) es += __shfl_xor(es, o);

  float bv = wgt[0]; int bi = c;
#pragma unroll
  for (int m = 1; m < 4; ++m) {
    if (wgt[m] > bv) { bv = wgt[m]; bi = c + 16 * m; }
  }
  for (int o = 1; o < 16; o <<= 1) {
    float ov = __shfl_xor(bv, o);
    int oi = __shfl_xor(bi, o);
    if (ov > bv || (ov == bv && oi < bi)) { bv = ov; bi = oi; }
  }
  if (c == 0) {
    atomicAdd(entSlot, -es * (1.0f / (float)B_ROWS));
    outPid[row] = (float)bi;
  }

  wl[r][c] = wgt[0]; wl[r][c + 16] = wgt[1]; wl[r][c + 32] = wgt[2]; wl[r][c + 48] = wgt[3];
  __syncthreads();
  float accv[4] = {0.f, 0.f, 0.f, 0.f};
#pragma unroll 16
  for (int k = 0; k < 64; ++k) {
    const float wv = wl[r][k];
    accv[0] = fmaf(wv, al[k][c], accv[0]);
    accv[1] = fmaf(wv, al[k][c + 16], accv[1]);
    accv[2] = fmaf(wv, al[k][c + 32], accv[2]);
    accv[3] = fmaf(wv, al[k][c + 48], accv[3]);
  }
  const size_t ob = (size_t)row * 64;
  outAct[ob + c]      = accv[0];
  outAct[ob + c + 16] = accv[1];
  outAct[ob + c + 32] = accv[2];
  outAct[ob + c + 48] = accv[3];
}

extern "C" void kernel_launch(void* const* d_in, const int* in_sizes, int n_in,
                              void* d_out, int out_size, void* d_ws, size_t ws_size,
                              hipStream_t stream) {
  (void)in_sizes; (void)n_in; (void)out_size; (void)ws_size;
  const float* h       = (const float*)d_in[0];
  const float* projW   = (const float*)d_in[1];
  const float* synW    = (const float*)d_in[2];
  const float* mask    = (const float*)d_in[3];
  const float* protos  = (const float*)d_in[4];
  const float* actions = (const float*)d_in[5];
  const float* gates   = (const float*)d_in[6];
  float* out = (float*)d_out;

  // ws layout
  unsigned short* hHi  = (unsigned short*)d_ws;
  unsigned short* hLo  = hHi + (size_t)B_ROWS * H_DIM;
  unsigned short* mtHi = hLo + (size_t)B_ROWS * H_DIM;
  unsigned short* TtHi = mtHi + (size_t)H_DIM * H_DIM;
  unsigned short* TtLo = TtHi + (size_t)64 * H_DIM;
  unsigned short* RtHi = TtLo + (size_t)64 * H_DIM;
  unsigned short* RtLo = RtHi + (size_t)64 * H_DIM;
  float* pn    = (float*)(RtLo + (size_t)64 * H_DIM);
  float* TP    = pn + (size_t)64 * H_DIM;
  float* RP    = TP + (size_t)8 * H_DIM * 64;
  float* simP  = RP + (size_t)8 * H_DIM * 64;
  float* normP = simP + (size_t)4 * B_ROWS * 64;

  proto_norm_kernel<<<64, 256, 0, stream>>>(protos, pn);
  gemmT_kernel<<<128, 256, 0, stream>>>(synW, mask, pn, TP);
  reduceTR_kernel<<<32, 256, 0, stream>>>(TP, TtHi, TtLo);
  gemmR_kernel<<<128, 256, 0, stream>>>(projW, TtHi, TtLo, RP);
  reduceTR_kernel<<<32, 256, 0, stream>>>(RP, RtHi, RtLo);
  split_kernel<<<2048, 256, 0, stream>>>(h, hHi, hLo, (B_ROWS * H_DIM) / 4);
  gemmM_kernel<<<256, 256, 0, stream>>>(synW, mask, projW, mtHi);
  normGemm_kernel<<<1024, 256, 0, stream>>>(hHi, mtHi, normP);
  simGemm_kernel<<<256, 256, 0, stream>>>(hHi, hLo, RtHi, RtLo, simP);
  hipMemsetAsync(out + 524288, 0, sizeof(float), stream);
  tail2_kernel<<<512, 256, 0, stream>>>(simP, normP, gates, actions,
                                        out, out + 524288, out + 524289);
}

// Round 4
// 234.975 us; speedup vs baseline: 4.7899x; 1.2094x over previous
//
#include <hip/hip_runtime.h>
#include <cstdint>

#define H_DIM 2048
#define B_ROWS 8192

typedef __attribute__((ext_vector_type(8))) short bf16x8;
typedef __attribute__((ext_vector_type(4))) float f32x4;
typedef __attribute__((ext_vector_type(4))) unsigned short u16x4;

static __device__ __forceinline__ float4 ld4(const float* p) {
  return *reinterpret_cast<const float4*>(p);
}

// round-to-nearest-even fp32 -> bf16 (raw ushort)
static __device__ __forceinline__ unsigned short f2bf(float x) {
  uint32_t b = __builtin_bit_cast(uint32_t, x);
  b += 0x7FFFu + ((b >> 16) & 1u);
  return (unsigned short)(b >> 16);
}
static __device__ __forceinline__ float bf2f(unsigned short h) {
  uint32_t b = ((uint32_t)h) << 16;
  return __builtin_bit_cast(float, b);
}

// MFMA fragment read from swizzled [rows][32-k] bf16 LDS tile.
static __device__ __forceinline__ bf16x8 fragld(const unsigned short* s, int row, int l) {
  const int blk = (l >> 4) ^ (row & 3) ^ ((row >> 2) & 3);
  return *reinterpret_cast<const bf16x8*>(s + row * 32 + blk * 8);
}

// ---------------- split h (fp32 -> hi/lo bf16) ----------------
__global__ __launch_bounds__(256) void split_kernel(const float* __restrict__ x,
                                                    unsigned short* __restrict__ hi,
                                                    unsigned short* __restrict__ lo,
                                                    int n4) {
  int i = blockIdx.x * 256 + threadIdx.x;
  const int stride = gridDim.x * 256;
  for (; i < n4; i += stride) {
    float4 v = ld4(x + (size_t)i * 4);
    u16x4 h, lw;
    unsigned short t;
    t = f2bf(v.x); h[0] = t; lw[0] = f2bf(v.x - bf2f(t));
    t = f2bf(v.y); h[1] = t; lw[1] = f2bf(v.y - bf2f(t));
    t = f2bf(v.z); h[2] = t; lw[2] = f2bf(v.z - bf2f(t));
    t = f2bf(v.w); h[3] = t; lw[3] = f2bf(v.w - bf2f(t));
    *reinterpret_cast<u16x4*>(hi + (size_t)i * 4) = h;
    *reinterpret_cast<u16x4*>(lo + (size_t)i * 4) = lw;
  }
}

// ---------------- prepT: transpose-convert weights to bf16 ----------------
// STt[j][o] = bf16(synW[o][j]*mask[o][j]) ; PWt[i][o] = bf16(projW[o][i])
// 64x64 fp32 tile via LDS; grid 1024 = 32 o-tiles x 32 col-tiles.
__global__ __launch_bounds__(256) void prepT_kernel(const float* __restrict__ synW,
                                                    const float* __restrict__ mask,
                                                    const float* __restrict__ projW,
                                                    unsigned short* __restrict__ STt,
                                                    unsigned short* __restrict__ PWt) {
  __shared__ float lt[64][65];
  const int tid = threadIdx.x;
  const int tr = (blockIdx.x >> 5) * 64;   // o base
  const int tc = (blockIdx.x & 31) * 64;   // col base
  const int r4 = tid >> 4, c4 = (tid & 15) * 4;
  const int j = tid >> 2, o0 = (tid & 3) * 16;
#pragma unroll
  for (int pass = 0; pass < 2; ++pass) {
    if (pass) __syncthreads();   // pass0 reads of lt complete before overwrite
#pragma unroll
    for (int rr = 0; rr < 4; ++rr) {
      const int row = rr * 16 + r4;
      float4 v;
      if (pass == 0) {
        float4 s = ld4(&synW[(size_t)(tr + row) * H_DIM + tc + c4]);
        float4 m = ld4(&mask[(size_t)(tr + row) * H_DIM + tc + c4]);
        v = make_float4(s.x * m.x, s.y * m.y, s.z * m.z, s.w * m.w);
      } else {
        v = ld4(&projW[(size_t)(tr + row) * H_DIM + tc + c4]);
      }
      lt[row][c4] = v.x; lt[row][c4 + 1] = v.y; lt[row][c4 + 2] = v.z; lt[row][c4 + 3] = v.w;
    }
    __syncthreads();
    unsigned short* dst = (pass == 0) ? STt : PWt;
    unsigned short* p = dst + (size_t)(tc + j) * H_DIM + tr + o0;
#pragma unroll
    for (int q = 0; q < 4; ++q) {
      u16x4 ov;
#pragma unroll
      for (int e = 0; e < 4; ++e) ov[e] = f2bf(lt[o0 + q * 4 + e][j]);
      *reinterpret_cast<u16x4*>(p + q * 4) = ov;
    }
  }
}

// ---------------- normalize protos ----------------
__global__ __launch_bounds__(256) void proto_norm_kernel(const float* __restrict__ protos,
                                                         float* __restrict__ pn) {
  const int k = blockIdx.x;
  const int tid = threadIdx.x;
  const float* row = protos + (size_t)k * H_DIM;
  float4 v0 = ld4(row + tid * 8);
  float4 v1 = ld4(row + tid * 8 + 4);
  float ss = v0.x*v0.x + v0.y*v0.y + v0.z*v0.z + v0.w*v0.w
           + v1.x*v1.x + v1.y*v1.y + v1.z*v1.z + v1.w*v1.w;
  for (int o = 32; o > 0; o >>= 1) ss += __shfl_down(ss, o);
  __shared__ float red[4];
  const int lane = tid & 63, wv = tid >> 6;
  if (lane == 0) red[wv] = ss;
  __syncthreads();
  const float tot = red[0] + red[1] + red[2] + red[3];
  const float inv = 1.0f / fmaxf(sqrtf(tot), 1e-12f);
  float* orow = pn + (size_t)k * H_DIM;
  *reinterpret_cast<float4*>(orow + tid*8)     = make_float4(v0.x*inv, v0.y*inv, v0.z*inv, v0.w*inv);
  *reinterpret_cast<float4*>(orow + tid*8 + 4) = make_float4(v1.x*inv, v1.y*inv, v1.z*inv, v1.w*inv);
}

// ---------------- gemmT: TP[os][o][p] = sum_{j in split} synWm[o][j]*pn[p][j] ----------------
__global__ __launch_bounds__(256, 2) void gemmT_kernel(const float* __restrict__ synW,
                                                       const float* __restrict__ mask,
                                                       const float* __restrict__ pn,
                                                       float* __restrict__ TP) {
  __shared__ unsigned short sAh[4096], sAl[4096], sBh[2048], sBl[2048];
  const int tid = threadIdx.x;
  const int l = tid & 63, w = tid >> 6;
  const int ot = blockIdx.x >> 3, os = blockIdx.x & 7;
  const int o0 = ot * 128;

  f32x4 acc[2][4];
#pragma unroll
  for (int mi = 0; mi < 2; ++mi)
#pragma unroll
    for (int ni = 0; ni < 4; ++ni) acc[mi][ni] = (f32x4){0.f, 0.f, 0.f, 0.f};

  const int rA0 = tid >> 2, ocA0 = tid & 3;
  const int rA1 = (tid + 256) >> 2, ocA1 = tid & 3;
  const int kB = tid >> 2, ocB = tid & 3;

  for (int it = 0; it < 8; ++it) {
    const int j0 = os * 256 + it * 32;
    bf16x8 aH[2], aL[2];
    int rr[2] = {rA0, rA1};
#pragma unroll
    for (int t = 0; t < 2; ++t) {
      const float* ps = synW + (size_t)(o0 + rr[t]) * H_DIM + j0 + ocA0 * 8;
      const float* pm = mask + (size_t)(o0 + rr[t]) * H_DIM + j0 + ocA0 * 8;
#pragma unroll
      for (int q = 0; q < 8; ++q) {
        float v = ps[q] * pm[q];
        unsigned short hv = f2bf(v);
        aH[t][q] = (short)hv; aL[t][q] = (short)f2bf(v - bf2f(hv));
      }
    }
    bf16x8 bH, bL;
    {
      const float* pp = pn + (size_t)kB * H_DIM + j0 + ocB * 8;
#pragma unroll
      for (int q = 0; q < 8; ++q) {
        float v = pp[q];
        unsigned short hv = f2bf(v);
        bH[q] = (short)hv; bL[q] = (short)f2bf(v - bf2f(hv));
      }
    }
    __syncthreads();
    {
      const int s0 = ocA0 ^ (rA0 & 3) ^ ((rA0 >> 2) & 3);
      const int s1 = ocA1 ^ (rA1 & 3) ^ ((rA1 >> 2) & 3);
      *reinterpret_cast<bf16x8*>(sAh + rA0 * 32 + s0 * 8) = aH[0];
      *reinterpret_cast<bf16x8*>(sAl + rA0 * 32 + s0 * 8) = aL[0];
      *reinterpret_cast<bf16x8*>(sAh + rA1 * 32 + s1 * 8) = aH[1];
      *reinterpret_cast<bf16x8*>(sAl + rA1 * 32 + s1 * 8) = aL[1];
      const int sb = ocB ^ (kB & 3) ^ ((kB >> 2) & 3);
      *reinterpret_cast<bf16x8*>(sBh + kB * 32 + sb * 8) = bH;
      *reinterpret_cast<bf16x8*>(sBl + kB * 32 + sb * 8) = bL;
    }
    __syncthreads();
    bf16x8 ah[2], al[2], bh[4], bl[4];
#pragma unroll
    for (int mi = 0; mi < 2; ++mi) {
      const int jr = w * 32 + mi * 16 + (l & 15);
      ah[mi] = fragld(sAh, jr, l); al[mi] = fragld(sAl, jr, l);
    }
#pragma unroll
    for (int ni = 0; ni < 4; ++ni) {
      const int jr = ni * 16 + (l & 15);
      bh[ni] = fragld(sBh, jr, l); bl[ni] = fragld(sBl, jr, l);
    }
#pragma unroll
    for (int mi = 0; mi < 2; ++mi)
#pragma unroll
      for (int ni = 0; ni < 4; ++ni) {
        acc[mi][ni] = __builtin_amdgcn_mfma_f32_16x16x32_bf16(ah[mi], bh[ni], acc[mi][ni], 0, 0, 0);
        acc[mi][ni] = __builtin_amdgcn_mfma_f32_16x16x32_bf16(ah[mi], bl[ni], acc[mi][ni], 0, 0, 0);
        acc[mi][ni] = __builtin_amdgcn_mfma_f32_16x16x32_bf16(al[mi], bh[ni], acc[mi][ni], 0, 0, 0);
        acc[mi][ni] = __builtin_amdgcn_mfma_f32_16x16x32_bf16(al[mi], bl[ni], acc[mi][ni], 0, 0, 0);
      }
  }
  const int r0 = (l >> 4) * 4, cc = l & 15;
#pragma unroll
  for (int mi = 0; mi < 2; ++mi)
#pragma unroll
    for (int ni = 0; ni < 4; ++ni)
#pragma unroll
      for (int r = 0; r < 4; ++r)
        TP[((size_t)os * H_DIM + o0 + w * 32 + mi * 16 + r0 + r) * 64 + ni * 16 + cc] =
            acc[mi][ni][r];
}

// ---------------- reduceTR: P[8][2048][64] -> dHi/dLo[64][2048] ----------------
__global__ __launch_bounds__(256) void reduceTR_kernel(const float* __restrict__ P,
                                                       unsigned short* __restrict__ dHi,
                                                       unsigned short* __restrict__ dLo) {
  __shared__ float lt[64][65];
  const int tid = threadIdx.x;
  const int a0 = blockIdx.x * 64;
  const int al = tid >> 2, b0 = (tid & 3) * 16;
  f32x4 a4[4];
#pragma unroll
  for (int q = 0; q < 4; ++q) a4[q] = (f32x4){0.f, 0.f, 0.f, 0.f};
  for (int s = 0; s < 8; ++s) {
    const float* p = P + ((size_t)s * H_DIM + a0 + al) * 64 + b0;
#pragma unroll
    for (int q = 0; q < 4; ++q) {
      f32x4 v = *reinterpret_cast<const f32x4*>(p + q * 4);
      a4[q] += v;
    }
  }
#pragma unroll
  for (int q = 0; q < 4; ++q)
#pragma unroll
    for (int e = 0; e < 4; ++e) lt[b0 + q * 4 + e][al] = a4[q][e];
  __syncthreads();
  const int b = tid >> 2, aq = (tid & 3) * 16;
  bf16x8 h0, h1, l0, l1;
#pragma unroll
  for (int jx = 0; jx < 8; ++jx) {
    float v = lt[b][aq + jx];
    unsigned short hv = f2bf(v);
    h0[jx] = (short)hv; l0[jx] = (short)f2bf(v - bf2f(hv));
    float v2 = lt[b][aq + 8 + jx];
    unsigned short hv2 = f2bf(v2);
    h1[jx] = (short)hv2; l1[jx] = (short)f2bf(v2 - bf2f(hv2));
  }
  unsigned short* oh = dHi + (size_t)b * H_DIM + a0 + aq;
  unsigned short* ol = dLo + (size_t)b * H_DIM + a0 + aq;
  *reinterpret_cast<bf16x8*>(oh) = h0; *reinterpret_cast<bf16x8*>(oh + 8) = h1;
  *reinterpret_cast<bf16x8*>(ol) = l0; *reinterpret_cast<bf16x8*>(ol + 8) = l1;
}

// ---------------- gemmR: RP[os][i][p] = sum_{o in split} projW[o][i]*Tt[p][o] ----------------
__global__ __launch_bounds__(256, 2) void gemmR_kernel(const float* __restrict__ projW,
                                                       const unsigned short* __restrict__ TtHi,
                                                       const unsigned short* __restrict__ TtLo,
                                                       float* __restrict__ RP) {
  __shared__ unsigned short sAh[4096], sAl[4096], sBh[2048], sBl[2048];
  const int tid = threadIdx.x;
  const int l = tid & 63, w = tid >> 6;
  const int itile = blockIdx.x >> 3, os = blockIdx.x & 7;
  const int i0 = itile * 128;
  const int jj = tid & 127, oh = tid >> 7;
  const int swzJ = (jj & 3) ^ ((jj >> 2) & 3);
  const int s0 = (oh * 2) ^ swzJ, s1 = (oh * 2 + 1) ^ swzJ;
  const int kB = tid >> 2, ocB = tid & 3;
  const int sb = ocB ^ (kB & 3) ^ ((kB >> 2) & 3);

  f32x4 acc[2][4];
#pragma unroll
  for (int mi = 0; mi < 2; ++mi)
#pragma unroll
    for (int ni = 0; ni < 4; ++ni) acc[mi][ni] = (f32x4){0.f, 0.f, 0.f, 0.f};

  for (int it = 0; it < 8; ++it) {
    const int o0 = os * 256 + it * 32;
    float av[16];
#pragma unroll
    for (int q = 0; q < 16; ++q)
      av[q] = projW[(size_t)(o0 + oh * 16 + q) * H_DIM + i0 + jj];
    bf16x8 aH0, aH1, aL0, aL1;
#pragma unroll
    for (int q = 0; q < 8; ++q) {
      unsigned short t;
      t = f2bf(av[q]);     aH0[q] = (short)t; aL0[q] = (short)f2bf(av[q] - bf2f(t));
      t = f2bf(av[q + 8]); aH1[q] = (short)t; aL1[q] = (short)f2bf(av[q + 8] - bf2f(t));
    }
    bf16x8 bH = *reinterpret_cast<const bf16x8*>(TtHi + (size_t)kB * H_DIM + o0 + ocB * 8);
    bf16x8 bL = *reinterpret_cast<const bf16x8*>(TtLo + (size_t)kB * H_DIM + o0 + ocB * 8);
    __syncthreads();
    *reinterpret_cast<bf16x8*>(sAh + jj * 32 + s0 * 8) = aH0;
    *reinterpret_cast<bf16x8*>(sAh + jj * 32 + s1 * 8) = aH1;
    *reinterpret_cast<bf16x8*>(sAl + jj * 32 + s0 * 8) = aL0;
    *reinterpret_cast<bf16x8*>(sAl + jj * 32 + s1 * 8) = aL1;
    *reinterpret_cast<bf16x8*>(sBh + kB * 32 + sb * 8) = bH;
    *reinterpret_cast<bf16x8*>(sBl + kB * 32 + sb * 8) = bL;
    __syncthreads();
    bf16x8 ah[2], al[2], bh[4], bl[4];
#pragma unroll
    for (int mi = 0; mi < 2; ++mi) {
      const int jr = w * 32 + mi * 16 + (l & 15);
      ah[mi] = fragld(sAh, jr, l); al[mi] = fragld(sAl, jr, l);
    }
#pragma unroll
    for (int ni = 0; ni < 4; ++ni) {
      const int jr = ni * 16 + (l & 15);
      bh[ni] = fragld(sBh, jr, l); bl[ni] = fragld(sBl, jr, l);
    }
#pragma unroll
    for (int mi = 0; mi < 2; ++mi)
#pragma unroll
      for (int ni = 0; ni < 4; ++ni) {
        acc[mi][ni] = __builtin_amdgcn_mfma_f32_16x16x32_bf16(ah[mi], bh[ni], acc[mi][ni], 0, 0, 0);
        acc[mi][ni] = __builtin_amdgcn_mfma_f32_16x16x32_bf16(ah[mi], bl[ni], acc[mi][ni], 0, 0, 0);
        acc[mi][ni] = __builtin_amdgcn_mfma_f32_16x16x32_bf16(al[mi], bh[ni], acc[mi][ni], 0, 0, 0);
        acc[mi][ni] = __builtin_amdgcn_mfma_f32_16x16x32_bf16(al[mi], bl[ni], acc[mi][ni], 0, 0, 0);
      }
  }
  const int r0 = (l >> 4) * 4, cc = l & 15;
#pragma unroll
  for (int mi = 0; mi < 2; ++mi)
#pragma unroll
    for (int ni = 0; ni < 4; ++ni)
#pragma unroll
      for (int r = 0; r < 4; ++r)
        RP[((size_t)os * H_DIM + i0 + w * 32 + mi * 16 + r0 + r) * 64 + ni * 16 + cc] =
            acc[mi][ni][r];
}

// ---------------- gemmM2: MP[ks][n][k] = sum_{o in ks-half} STt[n][o]*PWt[k][o] ----------------
// pure-bf16 m97 structure, global_load_lds staging, split-K=2
__global__ __launch_bounds__(256, 2) void gemmM2_kernel(const unsigned short* __restrict__ STt,
                                                        const unsigned short* __restrict__ PWt,
                                                        float* __restrict__ MP) {
  __shared__ unsigned short lds[8192];
  const int tid = threadIdx.x;
  const int l = tid & 63, w = tid >> 6;
  const int bid = blockIdx.x;
  const int wg = (bid & 7) * 64 + (bid >> 3);   // 512 % 8 == 0
  const int ks = wg >> 8;
  const int rem = wg & 255;
  const int n0 = (rem >> 4) * 128, kcol0 = (rem & 15) * 128;
  const int wm = w >> 1, wn = w & 1;

  f32x4 acc[4][4];
#pragma unroll
  for (int mi = 0; mi < 4; ++mi)
#pragma unroll
    for (int ni = 0; ni < 4; ++ni) acc[mi][ni] = (f32x4){0.f, 0.f, 0.f, 0.f};

  const unsigned short* src = (w < 2) ? STt : PWt;
  const int row0 = (w < 2) ? n0 : kcol0;
  unsigned short* dst = lds + (w >> 1) * 4096 + (w & 1) * 2048;
  const int jl = l >> 2;

  for (int o0 = ks * 1024; o0 < ks * 1024 + 1024; o0 += 32) {
#pragma unroll
    for (int i = 0; i < 4; ++i) {
      const int j = (w & 1) * 64 + i * 16 + jl;
      const int b = (l & 3) ^ (j & 3) ^ ((j >> 2) & 3);
      const unsigned short* g = src + (size_t)(row0 + j) * H_DIM + o0 + b * 8;
      __builtin_amdgcn_global_load_lds((const __attribute__((address_space(1))) void*)g,
                                       (__attribute__((address_space(3))) void*)(dst + i * 512),
                                       16, 0, 0);
    }
    __syncthreads();
    bf16x8 ah[4], bh[4];
#pragma unroll
    for (int mi = 0; mi < 4; ++mi) ah[mi] = fragld(lds, wm * 64 + mi * 16 + (l & 15), l);
#pragma unroll
    for (int ni = 0; ni < 4; ++ni) bh[ni] = fragld(lds + 4096, wn * 64 + ni * 16 + (l & 15), l);
#pragma unroll
    for (int mi = 0; mi < 4; ++mi)
#pragma unroll
      for (int ni = 0; ni < 4; ++ni)
        acc[mi][ni] = __builtin_amdgcn_mfma_f32_16x16x32_bf16(ah[mi], bh[ni], acc[mi][ni], 0, 0, 0);
    __syncthreads();
  }

  const int r0 = (l >> 4) * 4, cc = l & 15;
#pragma unroll
  for (int mi = 0; mi < 4; ++mi)
#pragma unroll
    for (int ni = 0; ni < 4; ++ni)
#pragma unroll
      for (int r = 0; r < 4; ++r)
        MP[((size_t)ks * H_DIM + n0 + wm * 64 + mi * 16 + r0 + r) * H_DIM
           + kcol0 + wn * 64 + ni * 16 + cc] = acc[mi][ni][r];
}

// ---------------- reduceM: mtHi[n][k] = bf16(MP[0][n][k] + MP[1][n][k]) ----------------
__global__ __launch_bounds__(256) void reduceM_kernel(const float* __restrict__ MP,
                                                      unsigned short* __restrict__ mtHi) {
  const int n4 = (H_DIM * H_DIM) / 4;
  int i = blockIdx.x * 256 + threadIdx.x;
  const int stride = gridDim.x * 256;
  for (; i < n4; i += stride) {
    f32x4 a = *reinterpret_cast<const f32x4*>(MP + (size_t)i * 4);
    f32x4 b = *reinterpret_cast<const f32x4*>(MP + (size_t)H_DIM * H_DIM + (size_t)i * 4);
    f32x4 s = a + b;
    u16x4 o;
#pragma unroll
    for (int e = 0; e < 4; ++e) o[e] = f2bf(s[e]);
    *reinterpret_cast<u16x4*>(mtHi + (size_t)i * 4) = o;
  }
}

// ---------------- normGemm: row-sumsq of (hHi @ mtHi), no C write ----------------
__global__ __launch_bounds__(256, 2) void normGemm_kernel(const unsigned short* __restrict__ hHi,
                                                          const unsigned short* __restrict__ mtHi,
                                                          float* __restrict__ normP) {
  __shared__ unsigned short lds[8192];
  const int tid = threadIdx.x;
  const int l = tid & 63, w = tid >> 6;
  const int bid = blockIdx.x;
  const int wg = (bid & 7) * 128 + (bid >> 3);
  const int m0 = (wg >> 4) * 128, nblk = wg & 15, n0 = nblk * 128;
  const int wm = w >> 1, wn = w & 1;

  f32x4 acc[4][4];
#pragma unroll
  for (int mi = 0; mi < 4; ++mi)
#pragma unroll
    for (int ni = 0; ni < 4; ++ni) acc[mi][ni] = (f32x4){0.f, 0.f, 0.f, 0.f};

  const unsigned short* src = (w < 2) ? hHi : mtHi;
  const int row0 = (w < 2) ? m0 : n0;
  unsigned short* dst = lds + (w >> 1) * 4096 + (w & 1) * 2048;
  const int jl = l >> 2;

  for (int k0 = 0; k0 < H_DIM; k0 += 32) {
#pragma unroll
    for (int i = 0; i < 4; ++i) {
      const int j = (w & 1) * 64 + i * 16 + jl;
      const int b = (l & 3) ^ (j & 3) ^ ((j >> 2) & 3);
      const unsigned short* g = src + (size_t)(row0 + j) * H_DIM + k0 + b * 8;
      __builtin_amdgcn_global_load_lds((const __attribute__((address_space(1))) void*)g,
                                       (__attribute__((address_space(3))) void*)(dst + i * 512),
                                       16, 0, 0);
    }
    __syncthreads();
    bf16x8 ah[4], bh[4];
#pragma unroll
    for (int mi = 0; mi < 4; ++mi) ah[mi] = fragld(lds, wm * 64 + mi * 16 + (l & 15), l);
#pragma unroll
    for (int ni = 0; ni < 4; ++ni) bh[ni] = fragld(lds + 4096, wn * 64 + ni * 16 + (l & 15), l);
#pragma unroll
    for (int mi = 0; mi < 4; ++mi)
#pragma unroll
      for (int ni = 0; ni < 4; ++ni)
        acc[mi][ni] = __builtin_amdgcn_mfma_f32_16x16x32_bf16(ah[mi], bh[ni], acc[mi][ni], 0, 0, 0);
    __syncthreads();
  }

  const int r0q = l >> 4, cc = l & 15;
#pragma unroll
  for (int mi = 0; mi < 4; ++mi) {
    float s[4] = {0.f, 0.f, 0.f, 0.f};
#pragma unroll
    for (int ni = 0; ni < 4; ++ni)
#pragma unroll
      for (int r = 0; r < 4; ++r) s[r] += acc[mi][ni][r] * acc[mi][ni][r];
#pragma unroll
    for (int r = 0; r < 4; ++r)
      for (int o = 1; o < 16; o <<= 1) s[r] += __shfl_xor(s[r], o);
    if (cc == 0) {
#pragma unroll
      for (int r = 0; r < 4; ++r)
        normP[(size_t)(m0 + wm * 64 + mi * 16 + r0q * 4 + r) * 32 + nblk * 2 + wn] = s[r];
    }
  }
}

// ---------------- simGemm: simP[os][b][p] = sum_{k in split} h[b][k]*Rt[p][k], 4-product ----------------
__global__ __launch_bounds__(256, 2) void simGemm_kernel(const unsigned short* __restrict__ hHi,
                                                         const unsigned short* __restrict__ hLo,
                                                         const unsigned short* __restrict__ RtHi,
                                                         const unsigned short* __restrict__ RtLo,
                                                         float* __restrict__ simP) {
  __shared__ unsigned short lds[12288];
  const int tid = threadIdx.x;
  const int l = tid & 63, w = tid >> 6;
  const int mt = blockIdx.x >> 2, os = blockIdx.x & 3;
  const int m0 = mt * 128;

  f32x4 acc[2][4];
#pragma unroll
  for (int mi = 0; mi < 2; ++mi)
#pragma unroll
    for (int ni = 0; ni < 4; ++ni) acc[mi][ni] = (f32x4){0.f, 0.f, 0.f, 0.f};

  const unsigned short* srcA = (w < 2) ? hHi : hLo;
  unsigned short* dstA = lds + (w >> 1) * 4096 + (w & 1) * 2048;
  unsigned short* dstBh = lds + 8192 + w * 512;
  unsigned short* dstBl = lds + 10240 + w * 512;
  const int jl = l >> 2;

  for (int it = 0; it < 16; ++it) {
    const int k0 = os * 512 + it * 32;
#pragma unroll
    for (int i = 0; i < 4; ++i) {
      const int j = (w & 1) * 64 + i * 16 + jl;
      const int b = (l & 3) ^ (j & 3) ^ ((j >> 2) & 3);
      const unsigned short* g = srcA + (size_t)(m0 + j) * H_DIM + k0 + b * 8;
      __builtin_amdgcn_global_load_lds((const __attribute__((address_space(1))) void*)g,
                                       (__attribute__((address_space(3))) void*)(dstA + i * 512),
                                       16, 0, 0);
    }
    {
      const int j = w * 16 + jl;
      const int b = (l & 3) ^ (j & 3) ^ ((j >> 2) & 3);
      const unsigned short* gh = RtHi + (size_t)j * H_DIM + k0 + b * 8;
      const unsigned short* gl = RtLo + (size_t)j * H_DIM + k0 + b * 8;
      __builtin_amdgcn_global_load_lds((const __attribute__((address_space(1))) void*)gh,
                                       (__attribute__((address_space(3))) void*)dstBh, 16, 0, 0);
      __builtin_amdgcn_global_load_lds((const __attribute__((address_space(1))) void*)gl,
                                       (__attribute__((address_space(3))) void*)dstBl, 16, 0, 0);
    }
    __syncthreads();
    bf16x8 ah[2], al[2], bh[4], bl[4];
#pragma unroll
    for (int mi = 0; mi < 2; ++mi) {
      const int j = w * 32 + mi * 16 + (l & 15);
      ah[mi] = fragld(lds, j, l); al[mi] = fragld(lds + 4096, j, l);
    }
#pragma unroll
    for (int ni = 0; ni < 4; ++ni) {
      const int j = ni * 16 + (l & 15);
      bh[ni] = fragld(lds + 8192, j, l); bl[ni] = fragld(lds + 10240, j, l);
    }
#pragma unroll
    for (int mi = 0; mi < 2; ++mi)
#pragma unroll
      for (int ni = 0; ni < 4; ++ni) {
        acc[mi][ni] = __builtin_amdgcn_mfma_f32_16x16x32_bf16(ah[mi], bh[ni], acc[mi][ni], 0, 0, 0);
        acc[mi][ni] = __builtin_amdgcn_mfma_f32_16x16x32_bf16(ah[mi], bl[ni], acc[mi][ni], 0, 0, 0);
        acc[mi][ni] = __builtin_amdgcn_mfma_f32_16x16x32_bf16(al[mi], bh[ni], acc[mi][ni], 0, 0, 0);
        acc[mi][ni] = __builtin_amdgcn_mfma_f32_16x16x32_bf16(al[mi], bl[ni], acc[mi][ni], 0, 0, 0);
      }
    __syncthreads();
  }
  const int r0 = (l >> 4) * 4, cc = l & 15;
#pragma unroll
  for (int mi = 0; mi < 2; ++mi)
#pragma unroll
    for (int ni = 0; ni < 4; ++ni)
#pragma unroll
      for (int r = 0; r < 4; ++r)
        simP[((size_t)os * B_ROWS + m0 + w * 32 + mi * 16 + r0 + r) * 64 + ni * 16 + cc] =
            acc[mi][ni][r];
}

// ---------------- tail ----------------
__global__ __launch_bounds__(256) void tail2_kernel(const float* __restrict__ simP,
                                                    const float* __restrict__ normP,
                                                    const float* __restrict__ gates,
                                                    const float* __restrict__ actions,
                                                    float* __restrict__ outAct,
                                                    float* __restrict__ entSlot,
                                                    float* __restrict__ outPid) {
  __shared__ float al[64][68];
  __shared__ float wl[16][68];
  const int tid = threadIdx.x;
  const int c = tid & 15, r = tid >> 4;
  const int b0 = blockIdx.x * 16;
  const int row = b0 + r;

#pragma unroll
  for (int t = 0; t < 4; ++t) {
    const int f = tid + t * 256;
    const int k = f >> 4, c4 = (f & 15) << 2;
    *reinterpret_cast<float4*>(&al[k][c4]) = ld4(&actions[k * 64 + c4]);
  }

  float sim[4];
#pragma unroll
  for (int m = 0; m < 4; ++m) {
    float s = 0.f;
#pragma unroll
    for (int os = 0; os < 4; ++os)
      s += simP[((size_t)os * B_ROWS + row) * 64 + c + 16 * m];
    sim[m] = s;
  }
  float nn = normP[(size_t)row * 32 + c] + normP[(size_t)row * 32 + c + 16];
  for (int o = 1; o < 16; o <<= 1) nn += __shfl_xor(nn, o);
  const float rninv = 1.0f / fmaxf(sqrtf(nn), 1e-12f);

  float g[4];
#pragma unroll
  for (int m = 0; m < 4; ++m) g[m] = sim[m] * rninv * gates[c + 16 * m];

  float mx = fmaxf(fmaxf(g[0], g[1]), fmaxf(g[2], g[3]));
  for (int o = 1; o < 16; o <<= 1) mx = fmaxf(mx, __shfl_xor(mx, o));
  float e[4], Z = 0.f;
#pragma unroll
  for (int m = 0; m < 4; ++m) { e[m] = expf(g[m] - mx); Z += e[m]; }
  for (int o = 1; o < 16; o <<= 1) Z += __shfl_xor(Z, o);
  const float invZ = 1.0f / Z;
  float wgt[4];
#pragma unroll
  for (int m = 0; m < 4; ++m) wgt[m] = e[m] * invZ;

  float es = 0.f;
#pragma unroll
  for (int m = 0; m < 4; ++m) es += wgt[m] * logf(wgt[m] + 1e-8f);
  for (int o = 1; o < 16; o <<= 1) es += __shfl_xor(es, o);

  float bv = wgt[0]; int bi = c;
#pragma unroll
  for (int m = 1; m < 4; ++m) {
    if (wgt[m] > bv) { bv = wgt[m]; bi = c + 16 * m; }
  }
  for (int o = 1; o < 16; o <<= 1) {
    float ov = __shfl_xor(bv, o);
    int oi = __shfl_xor(bi, o);
    if (ov > bv || (ov == bv && oi < bi)) { bv = ov; bi = oi; }
  }
  if (c == 0) {
    atomicAdd(entSlot, -es * (1.0f / (float)B_ROWS));
    outPid[row] = (float)bi;
  }

  wl[r][c] = wgt[0]; wl[r][c + 16] = wgt[1]; wl[r][c + 32] = wgt[2]; wl[r][c + 48] = wgt[3];
  __syncthreads();
  float accv[4] = {0.f, 0.f, 0.f, 0.f};
#pragma unroll 16
  for (int k = 0; k < 64; ++k) {
    const float wv = wl[r][k];
    accv[0] = fmaf(wv, al[k][c], accv[0]);
    accv[1] = fmaf(wv, al[k][c + 16], accv[1]);
    accv[2] = fmaf(wv, al[k][c + 32], accv[2]);
    accv[3] = fmaf(wv, al[k][c + 48], accv[3]);
  }
  const size_t ob = (size_t)row * 64;
  outAct[ob + c]      = accv[0];
  outAct[ob + c + 16] = accv[1];
  outAct[ob + c + 32] = accv[2];
  outAct[ob + c + 48] = accv[3];
}

extern "C" void kernel_launch(void* const* d_in, const int* in_sizes, int n_in,
                              void* d_out, int out_size, void* d_ws, size_t ws_size,
                              hipStream_t stream) {
  (void)in_sizes; (void)n_in; (void)out_size; (void)ws_size;
  const float* h       = (const float*)d_in[0];
  const float* projW   = (const float*)d_in[1];
  const float* synW    = (const float*)d_in[2];
  const float* mask    = (const float*)d_in[3];
  const float* protos  = (const float*)d_in[4];
  const float* actions = (const float*)d_in[5];
  const float* gates   = (const float*)d_in[6];
  float* out = (float*)d_out;

  // fixed buffers (ushort elements)
  unsigned short* hHi  = (unsigned short*)d_ws;
  unsigned short* hLo  = hHi + (size_t)B_ROWS * H_DIM;
  unsigned short* mtHi = hLo + (size_t)B_ROWS * H_DIM;
  unsigned short* STt  = mtHi + (size_t)H_DIM * H_DIM;
  unsigned short* PWt  = STt + (size_t)H_DIM * H_DIM;
  unsigned short* TtHi = PWt + (size_t)H_DIM * H_DIM;
  unsigned short* TtLo = TtHi + (size_t)64 * H_DIM;
  unsigned short* RtHi = TtLo + (size_t)64 * H_DIM;
  unsigned short* RtLo = RtHi + (size_t)64 * H_DIM;
  float* pn   = (float*)(RtLo + (size_t)64 * H_DIM);
  // aliased zone (32 MB): TP+RP -> MP -> normP+simP  (strictly ordered by launches)
  float* zone  = pn + (size_t)64 * H_DIM;
  float* TP    = zone;
  float* RP    = zone + (size_t)8 * H_DIM * 64;
  float* MP    = zone;
  float* normP = zone;
  float* simP  = zone + (size_t)B_ROWS * 32;

  prepT_kernel<<<1024, 256, 0, stream>>>(synW, mask, projW, STt, PWt);
  split_kernel<<<2048, 256, 0, stream>>>(h, hHi, hLo, (B_ROWS * H_DIM) / 4);
  proto_norm_kernel<<<64, 256, 0, stream>>>(protos, pn);
  gemmT_kernel<<<128, 256, 0, stream>>>(synW, mask, pn, TP);
  reduceTR_kernel<<<32, 256, 0, stream>>>(TP, TtHi, TtLo);
  gemmR_kernel<<<128, 256, 0, stream>>>(projW, TtHi, TtLo, RP);
  reduceTR_kernel<<<32, 256, 0, stream>>>(RP, RtHi, RtLo);
  gemmM2_kernel<<<512, 256, 0, stream>>>(STt, PWt, MP);
  reduceM_kernel<<<1024, 256, 0, stream>>>(MP, mtHi);
  normGemm_kernel<<<1024, 256, 0, stream>>>(hHi, mtHi, normP);
  simGemm_kernel<<<256, 256, 0, stream>>>(hHi, hLo, RtHi, RtLo, simP);
  hipMemsetAsync(out + 524288, 0, sizeof(float), stream);
  tail2_kernel<<<512, 256, 0, stream>>>(simP, normP, gates, actions,
                                        out, out + 524288, out + 524289);
}

// Round 5
// 216.257 us; speedup vs baseline: 5.2045x; 1.0866x over previous
//
#include <hip/hip_runtime.h>
#include <cstdint>

#define H_DIM 2048
#define B_ROWS 8192
#define NT 32   // K tiles of 64 in the 8-phase GEMM

typedef __attribute__((ext_vector_type(8))) short bf16x8;
typedef __attribute__((ext_vector_type(4))) float f32x4;
typedef __attribute__((ext_vector_type(4))) unsigned short u16x4;

static __device__ __forceinline__ float4 ld4(const float* p) {
  return *reinterpret_cast<const float4*>(p);
}

// round-to-nearest-even fp32 -> bf16 (raw ushort)
static __device__ __forceinline__ unsigned short f2bf(float x) {
  uint32_t b = __builtin_bit_cast(uint32_t, x);
  b += 0x7FFFu + ((b >> 16) & 1u);
  return (unsigned short)(b >> 16);
}
static __device__ __forceinline__ float bf2f(unsigned short h) {
  uint32_t b = ((uint32_t)h) << 16;
  return __builtin_bit_cast(float, b);
}

// MFMA fragment read from swizzled [rows][32-k] bf16 LDS tile (BK=32 kernels).
static __device__ __forceinline__ bf16x8 fragld(const unsigned short* s, int row, int l) {
  const int blk = (l >> 4) ^ (row & 3) ^ ((row >> 2) & 3);
  return *reinterpret_cast<const bf16x8*>(s + row * 32 + blk * 8);
}

// ---------------- split h (fp32 -> hi/lo bf16) ----------------
__global__ __launch_bounds__(256) void split_kernel(const float* __restrict__ x,
                                                    unsigned short* __restrict__ hi,
                                                    unsigned short* __restrict__ lo,
                                                    int n4) {
  int i = blockIdx.x * 256 + threadIdx.x;
  const int stride = gridDim.x * 256;
  for (; i < n4; i += stride) {
    float4 v = ld4(x + (size_t)i * 4);
    u16x4 h, lw;
    unsigned short t;
    t = f2bf(v.x); h[0] = t; lw[0] = f2bf(v.x - bf2f(t));
    t = f2bf(v.y); h[1] = t; lw[1] = f2bf(v.y - bf2f(t));
    t = f2bf(v.z); h[2] = t; lw[2] = f2bf(v.z - bf2f(t));
    t = f2bf(v.w); h[3] = t; lw[3] = f2bf(v.w - bf2f(t));
    *reinterpret_cast<u16x4*>(hi + (size_t)i * 4) = h;
    *reinterpret_cast<u16x4*>(lo + (size_t)i * 4) = lw;
  }
}

// ---------------- prepT: transpose-convert weights to bf16 ----------------
__global__ __launch_bounds__(256) void prepT_kernel(const float* __restrict__ synW,
                                                    const float* __restrict__ mask,
                                                    const float* __restrict__ projW,
                                                    unsigned short* __restrict__ STt,
                                                    unsigned short* __restrict__ PWt) {
  __shared__ float lt[64][65];
  const int tid = threadIdx.x;
  const int tr = (blockIdx.x >> 5) * 64;
  const int tc = (blockIdx.x & 31) * 64;
  const int r4 = tid >> 4, c4 = (tid & 15) * 4;
  const int j = tid >> 2, o0 = (tid & 3) * 16;
#pragma unroll
  for (int pass = 0; pass < 2; ++pass) {
    if (pass) __syncthreads();
#pragma unroll
    for (int rr = 0; rr < 4; ++rr) {
      const int row = rr * 16 + r4;
      float4 v;
      if (pass == 0) {
        float4 s = ld4(&synW[(size_t)(tr + row) * H_DIM + tc + c4]);
        float4 m = ld4(&mask[(size_t)(tr + row) * H_DIM + tc + c4]);
        v = make_float4(s.x * m.x, s.y * m.y, s.z * m.z, s.w * m.w);
      } else {
        v = ld4(&projW[(size_t)(tr + row) * H_DIM + tc + c4]);
      }
      lt[row][c4] = v.x; lt[row][c4 + 1] = v.y; lt[row][c4 + 2] = v.z; lt[row][c4 + 3] = v.w;
    }
    __syncthreads();
    unsigned short* dst = (pass == 0) ? STt : PWt;
    unsigned short* p = dst + (size_t)(tc + j) * H_DIM + tr + o0;
#pragma unroll
    for (int q = 0; q < 4; ++q) {
      u16x4 ov;
#pragma unroll
      for (int e = 0; e < 4; ++e) ov[e] = f2bf(lt[o0 + q * 4 + e][j]);
      *reinterpret_cast<u16x4*>(p + q * 4) = ov;
    }
  }
}

// ---------------- normalize protos ----------------
__global__ __launch_bounds__(256) void proto_norm_kernel(const float* __restrict__ protos,
                                                         float* __restrict__ pn) {
  const int k = blockIdx.x;
  const int tid = threadIdx.x;
  const float* row = protos + (size_t)k * H_DIM;
  float4 v0 = ld4(row + tid * 8);
  float4 v1 = ld4(row + tid * 8 + 4);
  float ss = v0.x*v0.x + v0.y*v0.y + v0.z*v0.z + v0.w*v0.w
           + v1.x*v1.x + v1.y*v1.y + v1.z*v1.z + v1.w*v1.w;
  for (int o = 32; o > 0; o >>= 1) ss += __shfl_down(ss, o);
  __shared__ float red[4];
  const int lane = tid & 63, wv = tid >> 6;
  if (lane == 0) red[wv] = ss;
  __syncthreads();
  const float tot = red[0] + red[1] + red[2] + red[3];
  const float inv = 1.0f / fmaxf(sqrtf(tot), 1e-12f);
  float* orow = pn + (size_t)k * H_DIM;
  *reinterpret_cast<float4*>(orow + tid*8)     = make_float4(v0.x*inv, v0.y*inv, v0.z*inv, v0.w*inv);
  *reinterpret_cast<float4*>(orow + tid*8 + 4) = make_float4(v1.x*inv, v1.y*inv, v1.z*inv, v1.w*inv);
}

// ---------------- gemmT: TP[os][o][p] = sum_{j in split} synWm[o][j]*pn[p][j] ----------------
__global__ __launch_bounds__(256, 2) void gemmT_kernel(const float* __restrict__ synW,
                                                       const float* __restrict__ mask,
                                                       const float* __restrict__ pn,
                                                       float* __restrict__ TP) {
  __shared__ unsigned short sAh[4096], sAl[4096], sBh[2048], sBl[2048];
  const int tid = threadIdx.x;
  const int l = tid & 63, w = tid >> 6;
  const int ot = blockIdx.x >> 3, os = blockIdx.x & 7;
  const int o0 = ot * 128;

  f32x4 acc[2][4];
#pragma unroll
  for (int mi = 0; mi < 2; ++mi)
#pragma unroll
    for (int ni = 0; ni < 4; ++ni) acc[mi][ni] = (f32x4){0.f, 0.f, 0.f, 0.f};

  const int rA0 = tid >> 2, ocA0 = tid & 3;
  const int rA1 = (tid + 256) >> 2, ocA1 = tid & 3;
  const int kB = tid >> 2, ocB = tid & 3;

  for (int it = 0; it < 8; ++it) {
    const int j0 = os * 256 + it * 32;
    bf16x8 aH[2], aL[2];
    int rr[2] = {rA0, rA1};
#pragma unroll
    for (int t = 0; t < 2; ++t) {
      const float* ps = synW + (size_t)(o0 + rr[t]) * H_DIM + j0 + ocA0 * 8;
      const float* pm = mask + (size_t)(o0 + rr[t]) * H_DIM + j0 + ocA0 * 8;
#pragma unroll
      for (int q = 0; q < 8; ++q) {
        float v = ps[q] * pm[q];
        unsigned short hv = f2bf(v);
        aH[t][q] = (short)hv; aL[t][q] = (short)f2bf(v - bf2f(hv));
      }
    }
    bf16x8 bH, bL;
    {
      const float* pp = pn + (size_t)kB * H_DIM + j0 + ocB * 8;
#pragma unroll
      for (int q = 0; q < 8; ++q) {
        float v = pp[q];
        unsigned short hv = f2bf(v);
        bH[q] = (short)hv; bL[q] = (short)f2bf(v - bf2f(hv));
      }
    }
    __syncthreads();
    {
      const int s0 = ocA0 ^ (rA0 & 3) ^ ((rA0 >> 2) & 3);
      const int s1 = ocA1 ^ (rA1 & 3) ^ ((rA1 >> 2) & 3);
      *reinterpret_cast<bf16x8*>(sAh + rA0 * 32 + s0 * 8) = aH[0];
      *reinterpret_cast<bf16x8*>(sAl + rA0 * 32 + s0 * 8) = aL[0];
      *reinterpret_cast<bf16x8*>(sAh + rA1 * 32 + s1 * 8) = aH[1];
      *reinterpret_cast<bf16x8*>(sAl + rA1 * 32 + s1 * 8) = aL[1];
      const int sb = ocB ^ (kB & 3) ^ ((kB >> 2) & 3);
      *reinterpret_cast<bf16x8*>(sBh + kB * 32 + sb * 8) = bH;
      *reinterpret_cast<bf16x8*>(sBl + kB * 32 + sb * 8) = bL;
    }
    __syncthreads();
    bf16x8 ah[2], al[2], bh[4], bl[4];
#pragma unroll
    for (int mi = 0; mi < 2; ++mi) {
      const int jr = w * 32 + mi * 16 + (l & 15);
      ah[mi] = fragld(sAh, jr, l); al[mi] = fragld(sAl, jr, l);
    }
#pragma unroll
    for (int ni = 0; ni < 4; ++ni) {
      const int jr = ni * 16 + (l & 15);
      bh[ni] = fragld(sBh, jr, l); bl[ni] = fragld(sBl, jr, l);
    }
#pragma unroll
    for (int mi = 0; mi < 2; ++mi)
#pragma unroll
      for (int ni = 0; ni < 4; ++ni) {
        acc[mi][ni] = __builtin_amdgcn_mfma_f32_16x16x32_bf16(ah[mi], bh[ni], acc[mi][ni], 0, 0, 0);
        acc[mi][ni] = __builtin_amdgcn_mfma_f32_16x16x32_bf16(ah[mi], bl[ni], acc[mi][ni], 0, 0, 0);
        acc[mi][ni] = __builtin_amdgcn_mfma_f32_16x16x32_bf16(al[mi], bh[ni], acc[mi][ni], 0, 0, 0);
        acc[mi][ni] = __builtin_amdgcn_mfma_f32_16x16x32_bf16(al[mi], bl[ni], acc[mi][ni], 0, 0, 0);
      }
  }
  const int r0 = (l >> 4) * 4, cc = l & 15;
#pragma unroll
  for (int mi = 0; mi < 2; ++mi)
#pragma unroll
    for (int ni = 0; ni < 4; ++ni)
#pragma unroll
      for (int r = 0; r < 4; ++r)
        TP[((size_t)os * H_DIM + o0 + w * 32 + mi * 16 + r0 + r) * 64 + ni * 16 + cc] =
            acc[mi][ni][r];
}

// ---------------- reduceTR ----------------
__global__ __launch_bounds__(256) void reduceTR_kernel(const float* __restrict__ P,
                                                       unsigned short* __restrict__ dHi,
                                                       unsigned short* __restrict__ dLo) {
  __shared__ float lt[64][65];
  const int tid = threadIdx.x;
  const int a0 = blockIdx.x * 64;
  const int al = tid >> 2, b0 = (tid & 3) * 16;
  f32x4 a4[4];
#pragma unroll
  for (int q = 0; q < 4; ++q) a4[q] = (f32x4){0.f, 0.f, 0.f, 0.f};
  for (int s = 0; s < 8; ++s) {
    const float* p = P + ((size_t)s * H_DIM + a0 + al) * 64 + b0;
#pragma unroll
    for (int q = 0; q < 4; ++q) {
      f32x4 v = *reinterpret_cast<const f32x4*>(p + q * 4);
      a4[q] += v;
    }
  }
#pragma unroll
  for (int q = 0; q < 4; ++q)
#pragma unroll
    for (int e = 0; e < 4; ++e) lt[b0 + q * 4 + e][al] = a4[q][e];
  __syncthreads();
  const int b = tid >> 2, aq = (tid & 3) * 16;
  bf16x8 h0, h1, l0, l1;
#pragma unroll
  for (int jx = 0; jx < 8; ++jx) {
    float v = lt[b][aq + jx];
    unsigned short hv = f2bf(v);
    h0[jx] = (short)hv; l0[jx] = (short)f2bf(v - bf2f(hv));
    float v2 = lt[b][aq + 8 + jx];
    unsigned short hv2 = f2bf(v2);
    h1[jx] = (short)hv2; l1[jx] = (short)f2bf(v2 - bf2f(hv2));
  }
  unsigned short* oh = dHi + (size_t)b * H_DIM + a0 + aq;
  unsigned short* ol = dLo + (size_t)b * H_DIM + a0 + aq;
  *reinterpret_cast<bf16x8*>(oh) = h0; *reinterpret_cast<bf16x8*>(oh + 8) = h1;
  *reinterpret_cast<bf16x8*>(ol) = l0; *reinterpret_cast<bf16x8*>(ol + 8) = l1;
}

// ---------------- gemmR ----------------
__global__ __launch_bounds__(256, 2) void gemmR_kernel(const float* __restrict__ projW,
                                                       const unsigned short* __restrict__ TtHi,
                                                       const unsigned short* __restrict__ TtLo,
                                                       float* __restrict__ RP) {
  __shared__ unsigned short sAh[4096], sAl[4096], sBh[2048], sBl[2048];
  const int tid = threadIdx.x;
  const int l = tid & 63, w = tid >> 6;
  const int itile = blockIdx.x >> 3, os = blockIdx.x & 7;
  const int i0 = itile * 128;
  const int jj = tid & 127, oh = tid >> 7;
  const int swzJ = (jj & 3) ^ ((jj >> 2) & 3);
  const int s0 = (oh * 2) ^ swzJ, s1 = (oh * 2 + 1) ^ swzJ;
  const int kB = tid >> 2, ocB = tid & 3;
  const int sb = ocB ^ (kB & 3) ^ ((kB >> 2) & 3);

  f32x4 acc[2][4];
#pragma unroll
  for (int mi = 0; mi < 2; ++mi)
#pragma unroll
    for (int ni = 0; ni < 4; ++ni) acc[mi][ni] = (f32x4){0.f, 0.f, 0.f, 0.f};

  for (int it = 0; it < 8; ++it) {
    const int o0 = os * 256 + it * 32;
    float av[16];
#pragma unroll
    for (int q = 0; q < 16; ++q)
      av[q] = projW[(size_t)(o0 + oh * 16 + q) * H_DIM + i0 + jj];
    bf16x8 aH0, aH1, aL0, aL1;
#pragma unroll
    for (int q = 0; q < 8; ++q) {
      unsigned short t;
      t = f2bf(av[q]);     aH0[q] = (short)t; aL0[q] = (short)f2bf(av[q] - bf2f(t));
      t = f2bf(av[q + 8]); aH1[q] = (short)t; aL1[q] = (short)f2bf(av[q + 8] - bf2f(t));
    }
    bf16x8 bH = *reinterpret_cast<const bf16x8*>(TtHi + (size_t)kB * H_DIM + o0 + ocB * 8);
    bf16x8 bL = *reinterpret_cast<const bf16x8*>(TtLo + (size_t)kB * H_DIM + o0 + ocB * 8);
    __syncthreads();
    *reinterpret_cast<bf16x8*>(sAh + jj * 32 + s0 * 8) = aH0;
    *reinterpret_cast<bf16x8*>(sAh + jj * 32 + s1 * 8) = aH1;
    *reinterpret_cast<bf16x8*>(sAl + jj * 32 + s0 * 8) = aL0;
    *reinterpret_cast<bf16x8*>(sAl + jj * 32 + s1 * 8) = aL1;
    *reinterpret_cast<bf16x8*>(sBh + kB * 32 + sb * 8) = bH;
    *reinterpret_cast<bf16x8*>(sBl + kB * 32 + sb * 8) = bL;
    __syncthreads();
    bf16x8 ah[2], al[2], bh[4], bl[4];
#pragma unroll
    for (int mi = 0; mi < 2; ++mi) {
      const int jr = w * 32 + mi * 16 + (l & 15);
      ah[mi] = fragld(sAh, jr, l); al[mi] = fragld(sAl, jr, l);
    }
#pragma unroll
    for (int ni = 0; ni < 4; ++ni) {
      const int jr = ni * 16 + (l & 15);
      bh[ni] = fragld(sBh, jr, l); bl[ni] = fragld(sBl, jr, l);
    }
#pragma unroll
    for (int mi = 0; mi < 2; ++mi)
#pragma unroll
      for (int ni = 0; ni < 4; ++ni) {
        acc[mi][ni] = __builtin_amdgcn_mfma_f32_16x16x32_bf16(ah[mi], bh[ni], acc[mi][ni], 0, 0, 0);
        acc[mi][ni] = __builtin_amdgcn_mfma_f32_16x16x32_bf16(ah[mi], bl[ni], acc[mi][ni], 0, 0, 0);
        acc[mi][ni] = __builtin_amdgcn_mfma_f32_16x16x32_bf16(al[mi], bh[ni], acc[mi][ni], 0, 0, 0);
        acc[mi][ni] = __builtin_amdgcn_mfma_f32_16x16x32_bf16(al[mi], bl[ni], acc[mi][ni], 0, 0, 0);
      }
  }
  const int r0 = (l >> 4) * 4, cc = l & 15;
#pragma unroll
  for (int mi = 0; mi < 2; ++mi)
#pragma unroll
    for (int ni = 0; ni < 4; ++ni)
#pragma unroll
      for (int r = 0; r < 4; ++r)
        RP[((size_t)os * H_DIM + i0 + w * 32 + mi * 16 + r0 + r) * 64 + ni * 16 + cc] =
            acc[mi][ni][r];
}

// ---------------- gemmM2 (split-K=2, m97 structure) ----------------
__global__ __launch_bounds__(256, 2) void gemmM2_kernel(const unsigned short* __restrict__ STt,
                                                        const unsigned short* __restrict__ PWt,
                                                        float* __restrict__ MP) {
  __shared__ unsigned short lds[8192];
  const int tid = threadIdx.x;
  const int l = tid & 63, w = tid >> 6;
  const int bid = blockIdx.x;
  const int wg = (bid & 7) * 64 + (bid >> 3);
  const int ks = wg >> 8;
  const int rem = wg & 255;
  const int n0 = (rem >> 4) * 128, kcol0 = (rem & 15) * 128;
  const int wm = w >> 1, wn = w & 1;

  f32x4 acc[4][4];
#pragma unroll
  for (int mi = 0; mi < 4; ++mi)
#pragma unroll
    for (int ni = 0; ni < 4; ++ni) acc[mi][ni] = (f32x4){0.f, 0.f, 0.f, 0.f};

  const unsigned short* src = (w < 2) ? STt : PWt;
  const int row0 = (w < 2) ? n0 : kcol0;
  unsigned short* dst = lds + (w >> 1) * 4096 + (w & 1) * 2048;
  const int jl = l >> 2;

  for (int o0 = ks * 1024; o0 < ks * 1024 + 1024; o0 += 32) {
#pragma unroll
    for (int i = 0; i < 4; ++i) {
      const int j = (w & 1) * 64 + i * 16 + jl;
      const int b = (l & 3) ^ (j & 3) ^ ((j >> 2) & 3);
      const unsigned short* g = src + (size_t)(row0 + j) * H_DIM + o0 + b * 8;
      __builtin_amdgcn_global_load_lds((const __attribute__((address_space(1))) void*)g,
                                       (__attribute__((address_space(3))) void*)(dst + i * 512),
                                       16, 0, 0);
    }
    __syncthreads();
    bf16x8 ah[4], bh[4];
#pragma unroll
    for (int mi = 0; mi < 4; ++mi) ah[mi] = fragld(lds, wm * 64 + mi * 16 + (l & 15), l);
#pragma unroll
    for (int ni = 0; ni < 4; ++ni) bh[ni] = fragld(lds + 4096, wn * 64 + ni * 16 + (l & 15), l);
#pragma unroll
    for (int mi = 0; mi < 4; ++mi)
#pragma unroll
      for (int ni = 0; ni < 4; ++ni)
        acc[mi][ni] = __builtin_amdgcn_mfma_f32_16x16x32_bf16(ah[mi], bh[ni], acc[mi][ni], 0, 0, 0);
    __syncthreads();
  }

  const int r0 = (l >> 4) * 4, cc = l & 15;
#pragma unroll
  for (int mi = 0; mi < 4; ++mi)
#pragma unroll
    for (int ni = 0; ni < 4; ++ni)
#pragma unroll
      for (int r = 0; r < 4; ++r)
        MP[((size_t)ks * H_DIM + n0 + wm * 64 + mi * 16 + r0 + r) * H_DIM
           + kcol0 + wn * 64 + ni * 16 + cc] = acc[mi][ni][r];
}

// ---------------- reduceM ----------------
__global__ __launch_bounds__(256) void reduceM_kernel(const float* __restrict__ MP,
                                                      unsigned short* __restrict__ mtHi) {
  const int n4 = (H_DIM * H_DIM) / 4;
  int i = blockIdx.x * 256 + threadIdx.x;
  const int stride = gridDim.x * 256;
  for (; i < n4; i += stride) {
    f32x4 a = *reinterpret_cast<const f32x4*>(MP + (size_t)i * 4);
    f32x4 b = *reinterpret_cast<const f32x4*>(MP + (size_t)H_DIM * H_DIM + (size_t)i * 4);
    f32x4 s = a + b;
    u16x4 o;
#pragma unroll
    for (int e = 0; e < 4; ++e) o[e] = f2bf(s[e]);
    *reinterpret_cast<u16x4*>(mtHi + (size_t)i * 4) = o;
  }
}

// ---------------- normGemm8: 8-phase 256x256 row-sumsq GEMM ----------------
// hsyn[m][n] = sum_k hHi[m][k]*mtHi[n][k]; epilogue: normP[m][nt*4+wn] = sum_n hsyn^2
// BM=BN=256, BK=64, 8 waves (2m x 4n), 128KB LDS double-buffered.
// LDS tile: [256 rows][8 slots][8 bf16]; octet o of row j at slot o^(j&7).
// Stage stream per tile-window t: {B0(t+1), B1(t+1), Amq1(t+1), Amq0(t+2)}, vmcnt(4) @ ph1,ph4.
static __device__ __forceinline__ void stage_half(const unsigned short* __restrict__ src,
                                                  int gRowBase, int kb,
                                                  unsigned short* dstBase,
                                                  int w, int laneRow, int laneOct,
                                                  bool interleave, int q) {
#pragma unroll
  for (int i = 0; i < 2; ++i) {
    const int r0 = (w * 2 + i) * 8;
    const int j0 = interleave ? ((r0 & 63) + ((r0 >> 6) << 7) + q * 64) : (q * 128 + r0);
    const unsigned short* g = src + (size_t)(gRowBase + j0 + laneRow) * H_DIM + kb + laneOct * 8;
    __builtin_amdgcn_global_load_lds((const __attribute__((address_space(1))) void*)g,
                                     (__attribute__((address_space(3))) void*)(dstBase + j0 * 64),
                                     16, 0, 0);
  }
}
static __device__ __forceinline__ bf16x8 frag8(const unsigned short* base, int row, int ks, int l) {
  const int s = ((ks << 2) + (l >> 4)) ^ (row & 7);
  return *reinterpret_cast<const bf16x8*>(base + row * 64 + s * 8);
}

__global__ __launch_bounds__(512, 2) void normGemm8_kernel(const unsigned short* __restrict__ hHi,
                                                           const unsigned short* __restrict__ mtHi,
                                                           float* __restrict__ normP) {
  __shared__ unsigned short lds[65536];   // 128 KiB: [2 buf][A 16384 | B 16384] ushorts
  const int tid = threadIdx.x;
  const int l = tid & 63, w = tid >> 6;
  const int wm = w >> 2, wn = w & 3;
  const int bid = blockIdx.x;
  const int wg = (bid & 7) * 32 + (bid >> 3);     // 256 % 8 == 0 -> bijective
  const int mt = wg >> 3, nt = wg & 7;
  const int m0 = mt * 256, n0 = nt * 256;
  const int lr = l >> 3, lo = (l & 7) ^ (l >> 3);

  f32x4 acc[8][4];
#pragma unroll
  for (int mf = 0; mf < 8; ++mf)
#pragma unroll
    for (int nf = 0; nf < 4; ++nf) acc[mf][nf] = (f32x4){0.f, 0.f, 0.f, 0.f};

  // prologue: Amq0(0), B0(0), B1(0), Amq1(0), Amq0(1); vmcnt(4) -> {Amq1(0),Amq0(1)} in flight
  stage_half(hHi,  m0, 0,  lds,                 w, lr, lo, true,  0);
  stage_half(mtHi, n0, 0,  lds + 16384,         w, lr, lo, false, 0);
  stage_half(mtHi, n0, 0,  lds + 16384,         w, lr, lo, false, 1);
  stage_half(hHi,  m0, 0,  lds,                 w, lr, lo, true,  1);
  stage_half(hHi,  m0, 64, lds + 32768,         w, lr, lo, true,  0);
  asm volatile("s_waitcnt vmcnt(4)" ::: "memory");
  __builtin_amdgcn_s_barrier();

  const int arow0 = wm * 128 + (l & 15);
  const int brow0 = wn * 64 + (l & 15);

  for (int t = 0; t < NT; ++t) {
    const int d = t & 1;
    const unsigned short* Ab = lds + d * 32768;
    const unsigned short* Bb = Ab + 16384;
    unsigned short* An = lds + (d ^ 1) * 32768;
    unsigned short* Bn = An + 16384;
    unsigned short* Ac = lds + d * 32768;
    int t1 = t + 1; if (t1 >= NT) t1 = NT - 2 + (t1 & 1);
    int t2 = t + 2; if (t2 >= NT) t2 = NT - 2 + (t2 & 1);
    const int kb1 = t1 * 64, kb2 = t2 * 64;

    bf16x8 af[4], bf[4];

    // ---- phase 1: (mq0, ks0); stage B0(t+1); vmcnt(4) ----
#pragma unroll
    for (int f = 0; f < 4; ++f) bf[f] = frag8(Bb, brow0 + f * 16, 0, l);
#pragma unroll
    for (int f = 0; f < 4; ++f) af[f] = frag8(Ab, arow0 + f * 16, 0, l);
    stage_half(mtHi, n0, kb1, Bn, w, lr, lo, false, 0);
    __builtin_amdgcn_s_barrier();
    asm volatile("s_waitcnt lgkmcnt(0)" ::: "memory");
    __builtin_amdgcn_sched_barrier(0);
    __builtin_amdgcn_s_setprio(1);
#pragma unroll
    for (int f = 0; f < 4; ++f)
#pragma unroll
      for (int nf = 0; nf < 4; ++nf)
        acc[f][nf] = __builtin_amdgcn_mfma_f32_16x16x32_bf16(af[f], bf[nf], acc[f][nf], 0, 0, 0);
    __builtin_amdgcn_s_setprio(0);
    asm volatile("s_waitcnt vmcnt(4)" ::: "memory");
    __builtin_amdgcn_s_barrier();

    // ---- phase 2: (mq1, ks0); stage B1(t+1) ----
#pragma unroll
    for (int f = 0; f < 4; ++f) af[f] = frag8(Ab, arow0 + 64 + f * 16, 0, l);
    stage_half(mtHi, n0, kb1, Bn, w, lr, lo, false, 1);
    __builtin_amdgcn_s_barrier();
    asm volatile("s_waitcnt lgkmcnt(0)" ::: "memory");
    __builtin_amdgcn_sched_barrier(0);
    __builtin_amdgcn_s_setprio(1);
#pragma unroll
    for (int f = 0; f < 4; ++f)
#pragma unroll
      for (int nf = 0; nf < 4; ++nf)
        acc[4 + f][nf] = __builtin_amdgcn_mfma_f32_16x16x32_bf16(af[f], bf[nf], acc[4 + f][nf], 0, 0, 0);
    __builtin_amdgcn_s_setprio(0);
    __builtin_amdgcn_s_barrier();

    // ---- phase 3: (mq0, ks1); stage Amq1(t+1) ----
#pragma unroll
    for (int f = 0; f < 4; ++f) bf[f] = frag8(Bb, brow0 + f * 16, 1, l);
#pragma unroll
    for (int f = 0; f < 4; ++f) af[f] = frag8(Ab, arow0 + f * 16, 1, l);
    stage_half(hHi, m0, kb1, An, w, lr, lo, true, 1);
    __builtin_amdgcn_s_barrier();
    asm volatile("s_waitcnt lgkmcnt(0)" ::: "memory");
    __builtin_amdgcn_sched_barrier(0);
    __builtin_amdgcn_s_setprio(1);
#pragma unroll
    for (int f = 0; f < 4; ++f)
#pragma unroll
      for (int nf = 0; nf < 4; ++nf)
        acc[f][nf] = __builtin_amdgcn_mfma_f32_16x16x32_bf16(af[f], bf[nf], acc[f][nf], 0, 0, 0);
    __builtin_amdgcn_s_setprio(0);
    __builtin_amdgcn_s_barrier();

    // ---- phase 4: (mq1, ks1); stage Amq0(t+2) into CURRENT buffer; vmcnt(4) ----
#pragma unroll
    for (int f = 0; f < 4; ++f) af[f] = frag8(Ab, arow0 + 64 + f * 16, 1, l);
    stage_half(hHi, m0, kb2, Ac, w, lr, lo, true, 0);
    __builtin_amdgcn_s_barrier();
    asm volatile("s_waitcnt lgkmcnt(0)" ::: "memory");
    __builtin_amdgcn_sched_barrier(0);
    __builtin_amdgcn_s_setprio(1);
#pragma unroll
    for (int f = 0; f < 4; ++f)
#pragma unroll
      for (int nf = 0; nf < 4; ++nf)
        acc[4 + f][nf] = __builtin_amdgcn_mfma_f32_16x16x32_bf16(af[f], bf[nf], acc[4 + f][nf], 0, 0, 0);
    __builtin_amdgcn_s_setprio(0);
    asm volatile("s_waitcnt vmcnt(4)" ::: "memory");
    __builtin_amdgcn_s_barrier();
  }
  asm volatile("s_waitcnt vmcnt(0)" ::: "memory");

  // epilogue: row sum of squares over this block's 256 columns
#pragma unroll
  for (int mf = 0; mf < 8; ++mf) {
#pragma unroll
    for (int r = 0; r < 4; ++r) {
      float s = 0.f;
#pragma unroll
      for (int nf = 0; nf < 4; ++nf) s += acc[mf][nf][r] * acc[mf][nf][r];
      for (int o = 1; o < 16; o <<= 1) s += __shfl_xor(s, o);
      if ((l & 15) == 0) {
        const int row = m0 + wm * 128 + mf * 16 + (l >> 4) * 4 + r;
        normP[(size_t)row * 32 + nt * 4 + wn] = s;
      }
    }
  }
}

// ---------------- simGemm ----------------
__global__ __launch_bounds__(256, 2) void simGemm_kernel(const unsigned short* __restrict__ hHi,
                                                         const unsigned short* __restrict__ hLo,
                                                         const unsigned short* __restrict__ RtHi,
                                                         const unsigned short* __restrict__ RtLo,
                                                         float* __restrict__ simP) {
  __shared__ unsigned short lds[12288];
  const int tid = threadIdx.x;
  const int l = tid & 63, w = tid >> 6;
  const int mt = blockIdx.x >> 2, os = blockIdx.x & 3;
  const int m0 = mt * 128;

  f32x4 acc[2][4];
#pragma unroll
  for (int mi = 0; mi < 2; ++mi)
#pragma unroll
    for (int ni = 0; ni < 4; ++ni) acc[mi][ni] = (f32x4){0.f, 0.f, 0.f, 0.f};

  const unsigned short* srcA = (w < 2) ? hHi : hLo;
  unsigned short* dstA = lds + (w >> 1) * 4096 + (w & 1) * 2048;
  unsigned short* dstBh = lds + 8192 + w * 512;
  unsigned short* dstBl = lds + 10240 + w * 512;
  const int jl = l >> 2;

  for (int it = 0; it < 16; ++it) {
    const int k0 = os * 512 + it * 32;
#pragma unroll
    for (int i = 0; i < 4; ++i) {
      const int j = (w & 1) * 64 + i * 16 + jl;
      const int b = (l & 3) ^ (j & 3) ^ ((j >> 2) & 3);
      const unsigned short* g = srcA + (size_t)(m0 + j) * H_DIM + k0 + b * 8;
      __builtin_amdgcn_global_load_lds((const __attribute__((address_space(1))) void*)g,
                                       (__attribute__((address_space(3))) void*)(dstA + i * 512),
                                       16, 0, 0);
    }
    {
      const int j = w * 16 + jl;
      const int b = (l & 3) ^ (j & 3) ^ ((j >> 2) & 3);
      const unsigned short* gh = RtHi + (size_t)j * H_DIM + k0 + b * 8;
      const unsigned short* gl = RtLo + (size_t)j * H_DIM + k0 + b * 8;
      __builtin_amdgcn_global_load_lds((const __attribute__((address_space(1))) void*)gh,
                                       (__attribute__((address_space(3))) void*)dstBh, 16, 0, 0);
      __builtin_amdgcn_global_load_lds((const __attribute__((address_space(1))) void*)gl,
                                       (__attribute__((address_space(3))) void*)dstBl, 16, 0, 0);
    }
    __syncthreads();
    bf16x8 ah[2], al[2], bh[4], bl[4];
#pragma unroll
    for (int mi = 0; mi < 2; ++mi) {
      const int j = w * 32 + mi * 16 + (l & 15);
      ah[mi] = fragld(lds, j, l); al[mi] = fragld(lds + 4096, j, l);
    }
#pragma unroll
    for (int ni = 0; ni < 4; ++ni) {
      const int j = ni * 16 + (l & 15);
      bh[ni] = fragld(lds + 8192, j, l); bl[ni] = fragld(lds + 10240, j, l);
    }
#pragma unroll
    for (int mi = 0; mi < 2; ++mi)
#pragma unroll
      for (int ni = 0; ni < 4; ++ni) {
        acc[mi][ni] = __builtin_amdgcn_mfma_f32_16x16x32_bf16(ah[mi], bh[ni], acc[mi][ni], 0, 0, 0);
        acc[mi][ni] = __builtin_amdgcn_mfma_f32_16x16x32_bf16(ah[mi], bl[ni], acc[mi][ni], 0, 0, 0);
        acc[mi][ni] = __builtin_amdgcn_mfma_f32_16x16x32_bf16(al[mi], bh[ni], acc[mi][ni], 0, 0, 0);
        acc[mi][ni] = __builtin_amdgcn_mfma_f32_16x16x32_bf16(al[mi], bl[ni], acc[mi][ni], 0, 0, 0);
      }
    __syncthreads();
  }
  const int r0 = (l >> 4) * 4, cc = l & 15;
#pragma unroll
  for (int mi = 0; mi < 2; ++mi)
#pragma unroll
    for (int ni = 0; ni < 4; ++ni)
#pragma unroll
      for (int r = 0; r < 4; ++r)
        simP[((size_t)os * B_ROWS + m0 + w * 32 + mi * 16 + r0 + r) * 64 + ni * 16 + cc] =
            acc[mi][ni][r];
}

// ---------------- tail ----------------
__global__ __launch_bounds__(256) void tail2_kernel(const float* __restrict__ simP,
                                                    const float* __restrict__ normP,
                                                    const float* __restrict__ gates,
                                                    const float* __restrict__ actions,
                                                    float* __restrict__ outAct,
                                                    float* __restrict__ entSlot,
                                                    float* __restrict__ outPid) {
  __shared__ float al[64][68];
  __shared__ float wl[16][68];
  const int tid = threadIdx.x;
  const int c = tid & 15, r = tid >> 4;
  const int b0 = blockIdx.x * 16;
  const int row = b0 + r;

#pragma unroll
  for (int t = 0; t < 4; ++t) {
    const int f = tid + t * 256;
    const int k = f >> 4, c4 = (f & 15) << 2;
    *reinterpret_cast<float4*>(&al[k][c4]) = ld4(&actions[k * 64 + c4]);
  }

  float sim[4];
#pragma unroll
  for (int m = 0; m < 4; ++m) {
    float s = 0.f;
#pragma unroll
    for (int os = 0; os < 4; ++os)
      s += simP[((size_t)os * B_ROWS + row) * 64 + c + 16 * m];
    sim[m] = s;
  }
  float nn = normP[(size_t)row * 32 + c] + normP[(size_t)row * 32 + c + 16];
  for (int o = 1; o < 16; o <<= 1) nn += __shfl_xor(nn, o);
  const float rninv = 1.0f / fmaxf(sqrtf(nn), 1e-12f);

  float g[4];
#pragma unroll
  for (int m = 0; m < 4; ++m) g[m] = sim[m] * rninv * gates[c + 16 * m];

  float mx = fmaxf(fmaxf(g[0], g[1]), fmaxf(g[2], g[3]));
  for (int o = 1; o < 16; o <<= 1) mx = fmaxf(mx, __shfl_xor(mx, o));
  float e[4], Z = 0.f;
#pragma unroll
  for (int m = 0; m < 4; ++m) { e[m] = expf(g[m] - mx); Z += e[m]; }
  for (int o = 1; o < 16; o <<= 1) Z += __shfl_xor(Z, o);
  const float invZ = 1.0f / Z;
  float wgt[4];
#pragma unroll
  for (int m = 0; m < 4; ++m) wgt[m] = e[m] * invZ;

  float es = 0.f;
#pragma unroll
  for (int m = 0; m < 4; ++m) es += wgt[m] * logf(wgt[m] + 1e-8f);
  for (int o = 1; o < 16; o <<= 1) es += __shfl_xor(es, o);

  float bv = wgt[0]; int bi = c;
#pragma unroll
  for (int m = 1; m < 4; ++m) {
    if (wgt[m] > bv) { bv = wgt[m]; bi = c + 16 * m; }
  }
  for (int o = 1; o < 16; o <<= 1) {
    float ov = __shfl_xor(bv, o);
    int oi = __shfl_xor(bi, o);
    if (ov > bv || (ov == bv && oi < bi)) { bv = ov; bi = oi; }
  }
  if (c == 0) {
    atomicAdd(entSlot, -es * (1.0f / (float)B_ROWS));
    outPid[row] = (float)bi;
  }

  wl[r][c] = wgt[0]; wl[r][c + 16] = wgt[1]; wl[r][c + 32] = wgt[2]; wl[r][c + 48] = wgt[3];
  __syncthreads();
  float accv[4] = {0.f, 0.f, 0.f, 0.f};
#pragma unroll 16
  for (int k = 0; k < 64; ++k) {
    const float wv = wl[r][k];
    accv[0] = fmaf(wv, al[k][c], accv[0]);
    accv[1] = fmaf(wv, al[k][c + 16], accv[1]);
    accv[2] = fmaf(wv, al[k][c + 32], accv[2]);
    accv[3] = fmaf(wv, al[k][c + 48], accv[3]);
  }
  const size_t ob = (size_t)row * 64;
  outAct[ob + c]      = accv[0];
  outAct[ob + c + 16] = accv[1];
  outAct[ob + c + 32] = accv[2];
  outAct[ob + c + 48] = accv[3];
}

extern "C" void kernel_launch(void* const* d_in, const int* in_sizes, int n_in,
                              void* d_out, int out_size, void* d_ws, size_t ws_size,
                              hipStream_t stream) {
  (void)in_sizes; (void)n_in; (void)out_size; (void)ws_size;
  const float* h       = (const float*)d_in[0];
  const float* projW   = (const float*)d_in[1];
  const float* synW    = (const float*)d_in[2];
  const float* mask    = (const float*)d_in[3];
  const float* protos  = (const float*)d_in[4];
  const float* actions = (const float*)d_in[5];
  const float* gates   = (const float*)d_in[6];
  float* out = (float*)d_out;

  unsigned short* hHi  = (unsigned short*)d_ws;
  unsigned short* hLo  = hHi + (size_t)B_ROWS * H_DIM;
  unsigned short* mtHi = hLo + (size_t)B_ROWS * H_DIM;
  unsigned short* STt  = mtHi + (size_t)H_DIM * H_DIM;
  unsigned short* PWt  = STt + (size_t)H_DIM * H_DIM;
  unsigned short* TtHi = PWt + (size_t)H_DIM * H_DIM;
  unsigned short* TtLo = TtHi + (size_t)64 * H_DIM;
  unsigned short* RtHi = TtLo + (size_t)64 * H_DIM;
  unsigned short* RtLo = RtHi + (size_t)64 * H_DIM;
  float* pn   = (float*)(RtLo + (size_t)64 * H_DIM);
  float* zone  = pn + (size_t)64 * H_DIM;
  float* TP    = zone;
  float* RP    = zone + (size_t)8 * H_DIM * 64;
  float* MP    = zone;
  float* normP = zone;
  float* simP  = zone + (size_t)B_ROWS * 32;

  prepT_kernel<<<1024, 256, 0, stream>>>(synW, mask, projW, STt, PWt);
  split_kernel<<<2048, 256, 0, stream>>>(h, hHi, hLo, (B_ROWS * H_DIM) / 4);
  proto_norm_kernel<<<64, 256, 0, stream>>>(protos, pn);
  gemmT_kernel<<<128, 256, 0, stream>>>(synW, mask, pn, TP);
  reduceTR_kernel<<<32, 256, 0, stream>>>(TP, TtHi, TtLo);
  gemmR_kernel<<<128, 256, 0, stream>>>(projW, TtHi, TtLo, RP);
  reduceTR_kernel<<<32, 256, 0, stream>>>(RP, RtHi, RtLo);
  gemmM2_kernel<<<512, 256, 0, stream>>>(STt, PWt, MP);
  reduceM_kernel<<<1024, 256, 0, stream>>>(MP, mtHi);
  normGemm8_kernel<<<256, 512, 0, stream>>>(hHi, mtHi, normP);
  simGemm_kernel<<<256, 256, 0, stream>>>(hHi, hLo, RtHi, RtLo, simP);
  hipMemsetAsync(out + 524288, 0, sizeof(float), stream);
  tail2_kernel<<<512, 256, 0, stream>>>(simP, normP, gates, actions,
                                        out, out + 524288, out + 524289);
}